// Round 2
// baseline (2340.522 us; speedup 1.0000x reference)
//
#include <hip/hip_runtime.h>
#include <hip/hip_bf16.h>
#include <math.h>

// Problem constants (B,T,E,H) = (4,2048,1024,16), D = 64
#define BB 4
#define TT 2048
#define EE 1024
#define HH 16
#define DD 64

#define F4(p) (*reinterpret_cast<const float4*>(p))
#define F4W(p) (*reinterpret_cast<float4*>(p))

// global -> LDS direct copy, 16B per lane. LDS dest must be wave-uniform;
// HW adds lane*16 itself.
__device__ __forceinline__ void gload16(const float* g, float* l) {
    __builtin_amdgcn_global_load_lds(
        (const __attribute__((address_space(1))) void*)g,
        (__attribute__((address_space(3))) void*)l, 16, 0, 0);
}

// ---------------------------------------------------------------------------
// Kernel 0: RoPE cos/sin table  [TT][DD/2] float2
// inv_freq computed in f64 then rounded to f32 (matches JAX's f32 value to
// 0.5 ulp), freq = t * inv_f32 (f32 rounding, like JAX), then f64 sin/cos.
// ---------------------------------------------------------------------------
__global__ void rope_table_kernel(float2* __restrict__ cs) {
    int idx = blockIdx.x * 256 + threadIdx.x;      // 0 .. 65535
    int t = idx >> 5;                              // position
    int i = idx & 31;                              // freq index (d/2)
    double inv_d = exp(((double)(-2 * i) / 64.0) * log(10000.0));
    float invf = (float)inv_d;
    float freq = (float)t * invf;
    double df = (double)freq;
    cs[idx] = make_float2((float)cos(df), (float)sin(df));
}

// ---------------------------------------------------------------------------
// Kernel 1: QKV = x @ W_attn + b_attn; epilogue RoPE(q,k) + scatter:
//   q_t, k_t : [B,H,D,T]  (transposed so flash can global_load_lds them)
//   v        : [B,H,T,D]
// M=8192, K=1024, N=3072. BM=BN=128, BK=16, 256 thr, 8x8 micro (2x2 of 4x4).
// B staged via global_load_lds double-buffer; A reg->LDS transposed.
// ---------------------------------------------------------------------------
__global__ __launch_bounds__(256) void qkv_rope_kernel(
    const float* __restrict__ x,      // [8192][1024]
    const float* __restrict__ W,      // [1024][3072]
    const float* __restrict__ bias,   // [3072]
    const float2* __restrict__ cs,    // [2048][32]
    float* __restrict__ qt_g, float* __restrict__ kt_g, float* __restrict__ v_g)
{
    __shared__ float As[16 * 128];      // [k][m]
    __shared__ float Bs[2][16 * 128];   // [k][n], double-buffered

    const int tid = threadIdx.x;
    const int tx = tid & 15, ty = tid >> 4;
    const int lane = tid & 63, wid = tid >> 6;
    const int n0 = blockIdx.x * 128;
    const int m0 = blockIdx.y * 128;

    const int arow = tid >> 1;           // 0..127
    const int akh  = (tid & 1) * 8;      // 0 or 8

    float acc[2][2][4][4] = {};

    // prologue: A regs for k0=0, B tile 0 via global_load_lds
    float4 av0 = F4(&x[(size_t)(m0 + arow) * 1024 + akh]);
    float4 av1 = F4(&x[(size_t)(m0 + arow) * 1024 + akh + 4]);
#pragma unroll
    for (int i = 0; i < 2; i++) {
        int c = wid * 2 + i;             // chunk = 2 rows of [16][128]
        gload16(&W[(size_t)(2 * c + (lane >> 5)) * 3072 + n0 + (lane & 31) * 4],
                &Bs[0][c * 256]);
    }

    int buf = 0;
    for (int k0 = 0; k0 < 1024; k0 += 16) {
        __syncthreads();                 // (a) B(buf) landed; prev LDS reads done
        As[(akh + 0) * 128 + arow] = av0.x;
        As[(akh + 1) * 128 + arow] = av0.y;
        As[(akh + 2) * 128 + arow] = av0.z;
        As[(akh + 3) * 128 + arow] = av0.w;
        As[(akh + 4) * 128 + arow] = av1.x;
        As[(akh + 5) * 128 + arow] = av1.y;
        As[(akh + 6) * 128 + arow] = av1.z;
        As[(akh + 7) * 128 + arow] = av1.w;
        __syncthreads();                 // (b) As visible; vmcnt empty here
        if (k0 + 16 < 1024) {
            av0 = F4(&x[(size_t)(m0 + arow) * 1024 + k0 + 16 + akh]);
            av1 = F4(&x[(size_t)(m0 + arow) * 1024 + k0 + 16 + akh + 4]);
#pragma unroll
            for (int i = 0; i < 2; i++) {
                int c = wid * 2 + i;
                gload16(&W[(size_t)(k0 + 16 + 2 * c + (lane >> 5)) * 3072 + n0 + (lane & 31) * 4],
                        &Bs[buf ^ 1][c * 256]);
            }
        }
        const float* Bp = Bs[buf];
#pragma unroll
        for (int kk = 0; kk < 16; kk++) {
            float4 a04 = F4(&As[kk * 128 + ty * 4]);
            float4 a14 = F4(&As[kk * 128 + 64 + ty * 4]);
            float4 b04 = F4(&Bp[kk * 128 + tx * 4]);
            float4 b14 = F4(&Bp[kk * 128 + 64 + tx * 4]);
            float ar[2][4] = {{a04.x, a04.y, a04.z, a04.w},
                              {a14.x, a14.y, a14.z, a14.w}};
            float br[2][4] = {{b04.x, b04.y, b04.z, b04.w},
                              {b14.x, b14.y, b14.z, b14.w}};
#pragma unroll
            for (int rh = 0; rh < 2; rh++)
#pragma unroll
                for (int ch = 0; ch < 2; ch++)
#pragma unroll
                    for (int i = 0; i < 4; i++)
#pragma unroll
                        for (int j = 0; j < 4; j++)
                            acc[rh][ch][i][j] += ar[rh][i] * br[ch][j];
        }
        buf ^= 1;
    }

    // Epilogue: bias + RoPE(q,k) + scatter
#pragma unroll
    for (int rh = 0; rh < 2; rh++) {
        const int mbase = m0 + rh * 64 + ty * 4;
        const int bb = mbase >> 11;
        const int t0 = mbase & 2047;          // 4 consecutive t
#pragma unroll
        for (int ch = 0; ch < 2; ch++) {
            const int n = n0 + ch * 64 + tx * 4;
            const int sec = n >> 10;          // 0=q 1=k 2=v
            const int e = n & 1023;
            const int hh = e >> 6, d = e & 63;
            float4 bi = F4(&bias[n]);
            float bcol[4] = {bi.x, bi.y, bi.z, bi.w};
            float vv[4][4];
#pragma unroll
            for (int i = 0; i < 4; i++)
#pragma unroll
                for (int j = 0; j < 4; j++)
                    vv[i][j] = acc[rh][ch][i][j] + bcol[j];

            if (sec == 2) {
#pragma unroll
                for (int i = 0; i < 4; i++) {
                    float4 w4 = make_float4(vv[i][0], vv[i][1], vv[i][2], vv[i][3]);
                    F4W(&v_g[((size_t)(bb * HH + hh) * TT + t0 + i) * 64 + d]) = w4;
                }
            } else {
                float r[4][4];
#pragma unroll
                for (int i = 0; i < 4; i++) {
                    float2 c0 = cs[(t0 + i) * 32 + (d >> 1)];
                    float2 c1 = cs[(t0 + i) * 32 + (d >> 1) + 1];
                    r[i][0] = vv[i][0] * c0.x - vv[i][1] * c0.y;
                    r[i][1] = vv[i][0] * c0.y + vv[i][1] * c0.x;
                    r[i][2] = vv[i][2] * c1.x - vv[i][3] * c1.y;
                    r[i][3] = vv[i][2] * c1.y + vv[i][3] * c1.x;
                }
                float* dst = (sec == 0) ? qt_g : kt_g;
#pragma unroll
                for (int j = 0; j < 4; j++) {
                    float4 w4 = make_float4(r[0][j], r[1][j], r[2][j], r[3][j]);
                    F4W(&dst[((size_t)(bb * HH + hh) * 64 + d + j) * TT + t0]) = w4;
                }
            }
        }
    }
}

// ---------------------------------------------------------------------------
// Kernel 2: fp32 flash attention. Block = (b, h, 128-row q tile), 256 thr.
// Q^T/K^T LDS tiles [64][128], V [128][64], all via global_load_lds.
// P [128 c][132] (fp32) overlays the K^T region (phase-disjoint).
// S microtile 8x8 (2x2 of 4-row x 4-col), O microtile 8x4.
// ---------------------------------------------------------------------------
__global__ __launch_bounds__(256, 1) void flash_kernel(
    const float* __restrict__ qt_g, const float* __restrict__ kt_g,
    const float* __restrict__ v_g, float* __restrict__ ao)
{
    __shared__ float Qs[64 * 128];       // Q^T [d][t-local]
    __shared__ float KPs[128 * 132];     // K^T [64][128] overlaid by Ps [128 c][132 r]
    __shared__ float Vs[128 * 64];       // V   [c][d]
    float* Ks = KPs;
    float* Ps = KPs;

    const int tid = threadIdx.x;
    const int tx = tid & 15, ty = tid >> 4;
    const int lane = tid & 63, wid = tid >> 6;
    const int qt = 15 - (int)blockIdx.x;        // long blocks first
    const int h = blockIdx.y, b = blockIdx.z;
    const int bh = b * HH + h;
    const int qpos0 = qt * 128;

    const float* qb = qt_g + (size_t)bh * 64 * TT;
    const float* kb = kt_g + (size_t)bh * 64 * TT;
    const float* vb = v_g  + (size_t)bh * TT * 64;

    // issue Q (32 chunks of 1024B: 2 d-rows each)
#pragma unroll
    for (int i = 0; i < 8; i++) {
        int c = wid * 8 + i;
        gload16(qb + (size_t)(2 * c + (lane >> 5)) * TT + qpos0 + (lane & 31) * 4,
                &Qs[c * 256]);
    }
    // issue K^T and V for kt=0
#pragma unroll
    for (int i = 0; i < 8; i++) {
        int c = wid * 8 + i;
        gload16(kb + (size_t)(2 * c + (lane >> 5)) * TT + (lane & 31) * 4, &KPs[c * 256]);
        gload16(vb + c * 256 + lane * 4, &Vs[c * 256]);
    }

    float m_i[2][4], l_i[2][4], o[2][4][4];
#pragma unroll
    for (int rh = 0; rh < 2; rh++)
#pragma unroll
        for (int i = 0; i < 4; i++) {
            m_i[rh][i] = -3.0e38f;
            l_i[rh][i] = 0.f;
#pragma unroll
            for (int j = 0; j < 4; j++) o[rh][i][j] = 0.f;
        }

    for (int kt = 0; kt <= qt; kt++) {
        __syncthreads();                 // (1) loads landed; prev PV done

        // ---- S = Q K^T ----
        float s[2][2][4][4] = {};
#pragma unroll 4
        for (int dd = 0; dd < 64; dd++) {
            float4 qa4 = F4(&Qs[dd * 128 + ty * 4]);
            float4 qb4 = F4(&Qs[dd * 128 + 64 + ty * 4]);
            float4 ka4 = F4(&Ks[dd * 128 + tx * 4]);
            float4 kb4 = F4(&Ks[dd * 128 + 64 + tx * 4]);
            float qr[2][4] = {{qa4.x, qa4.y, qa4.z, qa4.w},
                              {qb4.x, qb4.y, qb4.z, qb4.w}};
            float kr[2][4] = {{ka4.x, ka4.y, ka4.z, ka4.w},
                              {kb4.x, kb4.y, kb4.z, kb4.w}};
#pragma unroll
            for (int rh = 0; rh < 2; rh++)
#pragma unroll
                for (int ch = 0; ch < 2; ch++)
#pragma unroll
                    for (int i = 0; i < 4; i++)
#pragma unroll
                        for (int j = 0; j < 4; j++)
                            s[rh][ch][i][j] += qr[rh][i] * kr[ch][j];
        }
        __syncthreads();                 // (2) K reads done; region becomes Ps

        // ---- online softmax + P write ----
        const bool diag = (kt == qt);
#pragma unroll
        for (int rh = 0; rh < 2; rh++)
#pragma unroll
            for (int i = 0; i < 4; i++) {
                const int rl = rh * 64 + ty * 4 + i;
                float sv[8];
                float mloc = -3.0e38f;
#pragma unroll
                for (int ch = 0; ch < 2; ch++)
#pragma unroll
                    for (int j = 0; j < 4; j++) {
                        float val = s[rh][ch][i][j] * 0.125f;
                        if (diag) {
                            int cl = ch * 64 + tx * 4 + j;
                            if (cl > rl) val = -3.0e38f;
                        }
                        sv[ch * 4 + j] = val;
                        mloc = fmaxf(mloc, val);
                    }
#pragma unroll
                for (int off = 1; off < 16; off <<= 1)
                    mloc = fmaxf(mloc, __shfl_xor(mloc, off));
                const float mnew = fmaxf(m_i[rh][i], mloc);
                const float sc = __expf(m_i[rh][i] - mnew);
                float rs = 0.f;
#pragma unroll
                for (int ch = 0; ch < 2; ch++)
#pragma unroll
                    for (int j = 0; j < 4; j++) {
                        float p = __expf(sv[ch * 4 + j] - mnew);
                        Ps[(ch * 64 + tx * 4 + j) * 132 + rl] = p;
                        rs += p;
                    }
#pragma unroll
                for (int off = 1; off < 16; off <<= 1)
                    rs += __shfl_xor(rs, off);
                l_i[rh][i] = l_i[rh][i] * sc + rs;
                m_i[rh][i] = mnew;
#pragma unroll
                for (int j = 0; j < 4; j++) o[rh][i][j] *= sc;
            }
        __syncthreads();                 // (3) P visible

        // ---- O += P V ----
#pragma unroll 4
        for (int c = 0; c < 128; c++) {
            float4 pa4 = F4(&Ps[c * 132 + ty * 4]);
            float4 pb4 = F4(&Ps[c * 132 + 64 + ty * 4]);
            float4 vv4 = F4(&Vs[c * 64 + tx * 4]);
            float pr[2][4] = {{pa4.x, pa4.y, pa4.z, pa4.w},
                              {pb4.x, pb4.y, pb4.z, pb4.w}};
            float vr[4] = {vv4.x, vv4.y, vv4.z, vv4.w};
#pragma unroll
            for (int rh = 0; rh < 2; rh++)
#pragma unroll
                for (int i = 0; i < 4; i++)
#pragma unroll
                    for (int j = 0; j < 4; j++)
                        o[rh][i][j] += pr[rh][i] * vr[j];
        }

        if (kt < qt) {
            __syncthreads();             // (4) PV done everywhere; LDS free
            const int kp = (kt + 1) * 128;
#pragma unroll
            for (int i = 0; i < 8; i++) {
                int c = wid * 8 + i;
                gload16(kb + (size_t)(2 * c + (lane >> 5)) * TT + kp + (lane & 31) * 4,
                        &KPs[c * 256]);
                gload16(vb + (size_t)kp * 64 + c * 256 + lane * 4, &Vs[c * 256]);
            }
        }
    }

    // epilogue: normalize, write attn_out (B,T,E)
#pragma unroll
    for (int rh = 0; rh < 2; rh++)
#pragma unroll
        for (int i = 0; i < 4; i++) {
            const int t = qpos0 + rh * 64 + ty * 4 + i;
            const float inv = 1.0f / l_i[rh][i];
            float4 ov = make_float4(o[rh][i][0] * inv, o[rh][i][1] * inv,
                                    o[rh][i][2] * inv, o[rh][i][3] * inv);
            F4W(&ao[((size_t)(b * TT + t)) * EE + h * 64 + tx * 4]) = ov;
        }
}

// ---------------------------------------------------------------------------
// Kernel 3: out = attn_out @ W_proj + b_proj. M=8192, K=1024, N=1024.
// Same GEMM structure as kernel 1, no RoPE.
// ---------------------------------------------------------------------------
__global__ __launch_bounds__(256) void proj_kernel(
    const float* __restrict__ A,     // [8192][1024]
    const float* __restrict__ W,     // [1024][1024]
    const float* __restrict__ bias,  // [1024]
    float* __restrict__ out)         // [8192][1024]
{
    __shared__ float As[16 * 128];
    __shared__ float Bs[2][16 * 128];

    const int tid = threadIdx.x;
    const int tx = tid & 15, ty = tid >> 4;
    const int lane = tid & 63, wid = tid >> 6;
    const int n0 = blockIdx.x * 128;
    const int m0 = blockIdx.y * 128;

    const int arow = tid >> 1;
    const int akh  = (tid & 1) * 8;

    float acc[2][2][4][4] = {};

    float4 av0 = F4(&A[(size_t)(m0 + arow) * 1024 + akh]);
    float4 av1 = F4(&A[(size_t)(m0 + arow) * 1024 + akh + 4]);
#pragma unroll
    for (int i = 0; i < 2; i++) {
        int c = wid * 2 + i;
        gload16(&W[(size_t)(2 * c + (lane >> 5)) * 1024 + n0 + (lane & 31) * 4],
                &Bs[0][c * 256]);
    }

    int buf = 0;
    for (int k0 = 0; k0 < 1024; k0 += 16) {
        __syncthreads();
        As[(akh + 0) * 128 + arow] = av0.x;
        As[(akh + 1) * 128 + arow] = av0.y;
        As[(akh + 2) * 128 + arow] = av0.z;
        As[(akh + 3) * 128 + arow] = av0.w;
        As[(akh + 4) * 128 + arow] = av1.x;
        As[(akh + 5) * 128 + arow] = av1.y;
        As[(akh + 6) * 128 + arow] = av1.z;
        As[(akh + 7) * 128 + arow] = av1.w;
        __syncthreads();
        if (k0 + 16 < 1024) {
            av0 = F4(&A[(size_t)(m0 + arow) * 1024 + k0 + 16 + akh]);
            av1 = F4(&A[(size_t)(m0 + arow) * 1024 + k0 + 16 + akh + 4]);
#pragma unroll
            for (int i = 0; i < 2; i++) {
                int c = wid * 2 + i;
                gload16(&W[(size_t)(k0 + 16 + 2 * c + (lane >> 5)) * 1024 + n0 + (lane & 31) * 4],
                        &Bs[buf ^ 1][c * 256]);
            }
        }
        const float* Bp = Bs[buf];
#pragma unroll
        for (int kk = 0; kk < 16; kk++) {
            float4 a04 = F4(&As[kk * 128 + ty * 4]);
            float4 a14 = F4(&As[kk * 128 + 64 + ty * 4]);
            float4 b04 = F4(&Bp[kk * 128 + tx * 4]);
            float4 b14 = F4(&Bp[kk * 128 + 64 + tx * 4]);
            float ar[2][4] = {{a04.x, a04.y, a04.z, a04.w},
                              {a14.x, a14.y, a14.z, a14.w}};
            float br[2][4] = {{b04.x, b04.y, b04.z, b04.w},
                              {b14.x, b14.y, b14.z, b14.w}};
#pragma unroll
            for (int rh = 0; rh < 2; rh++)
#pragma unroll
                for (int ch = 0; ch < 2; ch++)
#pragma unroll
                    for (int i = 0; i < 4; i++)
#pragma unroll
                        for (int j = 0; j < 4; j++)
                            acc[rh][ch][i][j] += ar[rh][i] * br[ch][j];
        }
        buf ^= 1;
    }

#pragma unroll
    for (int rh = 0; rh < 2; rh++) {
        const int mbase = m0 + rh * 64 + ty * 4;
#pragma unroll
        for (int ch = 0; ch < 2; ch++) {
            const int n = n0 + ch * 64 + tx * 4;
            float4 bi = F4(&bias[n]);
            float bcol[4] = {bi.x, bi.y, bi.z, bi.w};
#pragma unroll
            for (int i = 0; i < 4; i++) {
                float4 w4 = make_float4(acc[rh][ch][i][0] + bcol[0],
                                        acc[rh][ch][i][1] + bcol[1],
                                        acc[rh][ch][i][2] + bcol[2],
                                        acc[rh][ch][i][3] + bcol[3]);
                F4W(&out[(size_t)(mbase + i) * 1024 + n]) = w4;
            }
        }
    }
}

// ---------------------------------------------------------------------------
extern "C" void kernel_launch(void* const* d_in, const int* in_sizes, int n_in,
                              void* d_out, int out_size, void* d_ws, size_t ws_size,
                              hipStream_t stream) {
    const float* x  = (const float*)d_in[0];   // [4,2048,1024]
    const float* Wa = (const float*)d_in[1];   // [1024,3072]
    const float* ba = (const float*)d_in[2];   // [3072]
    const float* Wp = (const float*)d_in[3];   // [1024,1024]
    const float* bp = (const float*)d_in[4];   // [1024]
    float* out = (float*)d_out;                // [4,2048,1024]

    // workspace layout (floats):
    //   q_t, k_t : 2 x 8388608  (B,H,D,T)
    //   v        : 8388608      (B,H,T,D)
    //   ao       : 8388608      (B,T,E)
    //   cs       : 131072       (T, D/2) float2
    float* ws = (float*)d_ws;
    float* q_t = ws;
    float* k_t = ws + 8388608;
    float* v   = ws + 16777216;
    float* ao  = ws + 25165824;
    float2* cs = (float2*)(ws + 33554432);

    rope_table_kernel<<<dim3(256), dim3(256), 0, stream>>>(cs);
    qkv_rope_kernel<<<dim3(24, 64), dim3(256), 0, stream>>>(x, Wa, ba, cs, q_t, k_t, v);
    flash_kernel<<<dim3(16, 16, 4), dim3(256), 0, stream>>>(q_t, k_t, v, ao);
    proj_kernel<<<dim3(8, 64), dim3(256), 0, stream>>>(ao, Wp, bp, out);
}

// Round 3
// 414.836 us; speedup vs baseline: 5.6420x; 5.6420x over previous
//
#include <hip/hip_runtime.h>
#include <hip/hip_bf16.h>
#include <math.h>

// (B,T,E,H) = (4,2048,1024,16), D=64
#define TT 2048
#define HH 16

typedef short s16x8 __attribute__((ext_vector_type(8)));
typedef float f32x4 __attribute__((ext_vector_type(4)));

#define F4(p) (*reinterpret_cast<const float4*>(p))

__device__ __forceinline__ void gload16(const void* g, void* l) {
    __builtin_amdgcn_global_load_lds(
        (const __attribute__((address_space(1))) void*)g,
        (__attribute__((address_space(3))) void*)l, 16, 0, 0);
}

__device__ __forceinline__ ushort f2b(float f) {
    uint u = __float_as_uint(f);
    uint r = (u + 0x7fffu + ((u >> 16) & 1u)) >> 16;
    return (ushort)r;
}

// ---------------------------------------------------------------------------
// RoPE cos/sin table [2048][32] float2
// ---------------------------------------------------------------------------
__global__ void rope_table_kernel(float2* __restrict__ cs) {
    int idx = blockIdx.x * 256 + threadIdx.x;      // 0..65535
    int t = idx >> 5;
    int i = idx & 31;
    double inv_d = exp(((double)(-2 * i) / 64.0) * log(10000.0));
    float invf = (float)inv_d;
    float freq = (float)t * invf;
    double df = (double)freq;
    cs[idx] = make_float2((float)cos(df), (float)sin(df));
}

// ---------------------------------------------------------------------------
// f32 -> bf16 convert (8 elems/thread, exact-size grid)
// ---------------------------------------------------------------------------
__global__ __launch_bounds__(256) void convert_f32_bf16(const float* __restrict__ in,
                                                        ushort* __restrict__ out) {
    size_t i = (size_t)(blockIdx.x * 256 + threadIdx.x) * 8;
    float4 a = F4(&in[i]); float4 b = F4(&in[i + 4]);
    s16x8 v;
    v[0] = f2b(a.x); v[1] = f2b(a.y); v[2] = f2b(a.z); v[3] = f2b(a.w);
    v[4] = f2b(b.x); v[5] = f2b(b.y); v[6] = f2b(b.z); v[7] = f2b(b.w);
    *reinterpret_cast<s16x8*>(&out[i]) = v;
}

// ---------------------------------------------------------------------------
// f32 [R][C] -> bf16 [C][R] transpose (64x64 tiles)
// ---------------------------------------------------------------------------
__global__ __launch_bounds__(256) void transpose_f32_bf16(const float* __restrict__ in,
                                                          ushort* __restrict__ out,
                                                          int R, int C) {
    __shared__ float t[64][65];
    int r0 = blockIdx.y * 64, c0 = blockIdx.x * 64;
    int ix = threadIdx.x & 15, iy = threadIdx.x >> 4;
#pragma unroll
    for (int j = 0; j < 4; ++j) {
        float4 v = F4(&in[(size_t)(r0 + iy + j * 16) * C + c0 + ix * 4]);
        t[iy + j * 16][ix * 4 + 0] = v.x;
        t[iy + j * 16][ix * 4 + 1] = v.y;
        t[iy + j * 16][ix * 4 + 2] = v.z;
        t[iy + j * 16][ix * 4 + 3] = v.w;
    }
    __syncthreads();
    int oc = threadIdx.x >> 2, seg = threadIdx.x & 3;
    s16x8 u0, u1;
#pragma unroll
    for (int i = 0; i < 8; ++i) u0[i] = f2b(t[seg * 16 + i][oc]);
#pragma unroll
    for (int i = 0; i < 8; ++i) u1[i] = f2b(t[seg * 16 + 8 + i][oc]);
    ushort* dst = &out[(size_t)(c0 + oc) * R + r0 + seg * 16];
    *reinterpret_cast<s16x8*>(dst) = u0;
    *reinterpret_cast<s16x8*>(dst + 8) = u1;
}

// ---------------------------------------------------------------------------
// v [bh][2048][64] bf16 -> vt [bh][64][2048] bf16
// ---------------------------------------------------------------------------
__global__ __launch_bounds__(256) void transpose_v_kernel(const ushort* __restrict__ vg,
                                                          ushort* __restrict__ vt) {
    __shared__ ushort t[64][72];
    int bh = blockIdx.y;
    int t0 = blockIdx.x * 64;
    const ushort* src = vg + (size_t)bh * 131072;
    int tid = threadIdx.x;
#pragma unroll
    for (int i = 0; i < 2; ++i) {
        int cid = tid * 2 + i;
        int row = cid >> 3, slot = cid & 7;
        s16x8 v = *reinterpret_cast<const s16x8*>(&src[(size_t)(t0 + row) * 64 + slot * 8]);
#pragma unroll
        for (int e = 0; e < 8; ++e) t[row][slot * 8 + e] = v[e];
    }
    __syncthreads();
    int od = tid >> 2, seg = tid & 3;
    s16x8 u0, u1;
#pragma unroll
    for (int i = 0; i < 8; ++i) u0[i] = t[seg * 16 + i][od];
#pragma unroll
    for (int i = 0; i < 8; ++i) u1[i] = t[seg * 16 + 8 + i][od];
    ushort* dst = vt + (size_t)bh * 131072 + (size_t)od * 2048 + t0 + seg * 16;
    *reinterpret_cast<s16x8*>(dst) = u0;
    *reinterpret_cast<s16x8*>(dst + 8) = u1;
}

// ---------------------------------------------------------------------------
// QKV GEMM bf16 MFMA: [8192x1024] @ [1024x3072] (+bias) -> rope -> q,k,v bf16
// BM=BN=128, BK=64, 256 thr (4 waves, 64x64 quadrants), dbuf LDS, XOR swizzle.
// ---------------------------------------------------------------------------
__global__ __launch_bounds__(256, 2) void qkv_gemm_kernel(
    const ushort* __restrict__ xb,    // [8192][1024] bf16
    const ushort* __restrict__ wat,   // [3072][1024] bf16 (W^T)
    const float* __restrict__ bias,   // [3072]
    const float2* __restrict__ cs,    // [2048][32]
    ushort* __restrict__ qg, ushort* __restrict__ kg, ushort* __restrict__ vg)
{
    __shared__ ushort As[2][8192];   // [128 m][64 k]
    __shared__ ushort Bs[2][8192];   // [128 n][64 k]

    const int tid = threadIdx.x;
    const int lane = tid & 63, wid = tid >> 6;
    const int lane15 = lane & 15, kgrp = lane >> 4;
    const int wr = wid >> 1, wc = wid & 1;
    const int m0 = blockIdx.y * 128, n0 = blockIdx.x * 128;
    const int swz = (lane15 & 7) << 4;
    const int srcsw = ((lane & 7) ^ ((lane >> 3) & 7)) * 8;
    const int kgrp16 = kgrp * 16;

    f32x4 acc[4][4] = {};

#define STAGE_QKV(bufi, kofs)                                                     \
    do {                                                                          \
        _Pragma("unroll")                                                         \
        for (int i_ = 0; i_ < 4; ++i_) {                                          \
            int c_ = wid * 4 + i_;                                                \
            gload16(xb + (size_t)(m0 + c_ * 8 + (lane >> 3)) * 1024 + (kofs) + srcsw, \
                    &As[bufi][c_ * 512]);                                         \
            gload16(wat + (size_t)(n0 + c_ * 8 + (lane >> 3)) * 1024 + (kofs) + srcsw, \
                    &Bs[bufi][c_ * 512]);                                         \
        }                                                                         \
    } while (0)

    STAGE_QKV(0, 0);
    int buf = 0;
    for (int kt = 0; kt < 16; ++kt) {
        __syncthreads();
        if (kt < 15) STAGE_QKV(buf ^ 1, (kt + 1) * 64);
        const char* Ap = (const char*)As[buf];
        const char* Bp = (const char*)Bs[buf];
#pragma unroll
        for (int ks = 0; ks < 2; ++ks) {
            s16x8 af[4], bfv[4];
            const int kb = (ks * 64 + kgrp16) ^ swz;
#pragma unroll
            for (int f = 0; f < 4; ++f) {
                int row = wr * 64 + f * 16 + lane15;
                af[f] = *reinterpret_cast<const s16x8*>(Ap + row * 128 + kb);
            }
#pragma unroll
            for (int g = 0; g < 4; ++g) {
                int row = wc * 64 + g * 16 + lane15;
                bfv[g] = *reinterpret_cast<const s16x8*>(Bp + row * 128 + kb);
            }
#pragma unroll
            for (int f = 0; f < 4; ++f)
#pragma unroll
                for (int g = 0; g < 4; ++g)
                    acc[f][g] = __builtin_amdgcn_mfma_f32_16x16x32_bf16(
                        af[f], bfv[g], acc[f][g], 0, 0, 0);
        }
        buf ^= 1;
    }

    // epilogue: bias + rope(q,k) + scatter bf16
#pragma unroll
    for (int g = 0; g < 4; ++g) {
        const int n = n0 + wc * 64 + g * 16 + lane15;
        const int sec = n >> 10;
        const int e = n & 1023;
        const int hh = e >> 6, d = e & 63;
        const float bsv = bias[n];
        ushort* dst = (sec == 0) ? qg : (sec == 1) ? kg : vg;
#pragma unroll
        for (int f = 0; f < 4; ++f) {
#pragma unroll
            for (int r = 0; r < 4; ++r) {
                const int m = m0 + wr * 64 + f * 16 + kgrp * 4 + r;
                float v = acc[f][g][r] + bsv;
                float p = __shfl_xor(v, 1);
                float rv;
                if (sec < 2) {
                    float2 c2 = cs[(m & 2047) * 32 + (d >> 1)];
                    rv = (d & 1) ? (p * c2.y + v * c2.x) : (v * c2.x - p * c2.y);
                } else {
                    rv = v;
                }
                dst[((size_t)((m >> 11) * HH + hh) * TT + (m & 2047)) * 64 + d] = f2b(rv);
            }
        }
    }
#undef STAGE_QKV
}

// ---------------------------------------------------------------------------
// Flash attention bf16 MFMA. Block = (qt 128 rows, h, b), 256 thr (4 waves).
// S^T = mfma(K, Q^T)  -> lane-local kv runs; online softmax (shfl 16/32);
// O^T = mfma(V^T, P^T). KV tiles 64, dbuf. 1 barrier/tile. 64KB LDS.
// ---------------------------------------------------------------------------
__global__ __launch_bounds__(256, 2) void flash_kernel(
    const ushort* __restrict__ qg, const ushort* __restrict__ kg,
    const ushort* __restrict__ vt, ushort* __restrict__ aob)
{
    __shared__ ushort Q_s[8192];      // [128 q][64 d]
    __shared__ ushort K_s[2][4096];   // [64 kv][64 d]
    __shared__ ushort V_s[2][4096];   // [64 d][64 kv]
    __shared__ ushort P_s[8192];      // [128 q][64 kv]; reused as Ao [128 q][64 d]

    const int tid = threadIdx.x;
    const int lane = tid & 63, wid = tid >> 6;
    const int lane15 = lane & 15, kgrp = lane >> 4;
    const int qt = 15 - (int)blockIdx.x;
    const int h = blockIdx.y, b = blockIdx.z;
    const int bh = b * HH + h;
    const int q0 = qt * 128;
    const int wq = wid * 32;
    const int swz = (lane15 & 7) << 4;
    const int srcsw = ((lane & 7) ^ ((lane >> 3) & 7)) * 8;
    const int kgrp16 = kgrp * 16;
    const int nt = 2 * qt + 2;

    const ushort* qp = qg + (size_t)bh * TT * 64;
    const ushort* kp = kg + (size_t)bh * TT * 64;
    const ushort* vp = vt + (size_t)bh * 64 * TT;

#define STAGE_KV(bufi, kv0_)                                                      \
    do {                                                                          \
        _Pragma("unroll")                                                         \
        for (int i_ = 0; i_ < 2; ++i_) {                                          \
            int c_ = wid * 2 + i_;                                                \
            gload16(kp + (size_t)((kv0_) + c_ * 8 + (lane >> 3)) * 64 + srcsw,    \
                    &K_s[bufi][c_ * 512]);                                        \
            gload16(vp + (size_t)(c_ * 8 + (lane >> 3)) * TT + (kv0_) + srcsw,    \
                    &V_s[bufi][c_ * 512]);                                        \
        }                                                                         \
    } while (0)

    // stage Q (once) + first KV tile
#pragma unroll
    for (int i = 0; i < 4; ++i) {
        int c = wid * 4 + i;
        gload16(qp + (size_t)(q0 + c * 8 + (lane >> 3)) * 64 + srcsw, &Q_s[c * 512]);
    }
    STAGE_KV(0, 0);

    f32x4 o[4][2] = {};
    float mreg[2] = {-3.0e38f, -3.0e38f};
    float lreg[2] = {0.f, 0.f};
    const float SCL = 0.125f * 1.44269504088896f;   // scale * log2(e)

    int buf = 0;
    for (int t = 0; t < nt; ++t) {
        __syncthreads();                         // staged cur ready; P free
        if (t + 1 < nt) STAGE_KV(buf ^ 1, (t + 1) * 64);

        const char* Kp = (const char*)K_s[buf];
        const char* Vp = (const char*)V_s[buf];
        const int kv0 = t * 64;

        // ---- S^T = K . Q^T ----
        f32x4 sacc[4][2] = {};
#pragma unroll
        for (int ks = 0; ks < 2; ++ks) {
            const int kb = (ks * 64 + kgrp16) ^ swz;
            s16x8 ka[4], qb[2];
#pragma unroll
            for (int kf = 0; kf < 4; ++kf) {
                int row = kf * 16 + lane15;
                ka[kf] = *reinterpret_cast<const s16x8*>(Kp + row * 128 + kb);
            }
#pragma unroll
            for (int qf = 0; qf < 2; ++qf) {
                int row = wq + qf * 16 + lane15;
                qb[qf] = *reinterpret_cast<const s16x8*>((const char*)Q_s + row * 128 + kb);
            }
#pragma unroll
            for (int kf = 0; kf < 4; ++kf)
#pragma unroll
                for (int qf = 0; qf < 2; ++qf)
                    sacc[kf][qf] = __builtin_amdgcn_mfma_f32_16x16x32_bf16(
                        ka[kf], qb[qf], sacc[kf][qf], 0, 0, 0);
        }

        // ---- online softmax (per lane: 2 q-cols x 16 kv-values) ----
        const bool masked = (t >= nt - 2);
#pragma unroll
        for (int qf = 0; qf < 2; ++qf) {
            const int qglob = q0 + wq + qf * 16 + lane15;
            float mx = -3.0e38f;
#pragma unroll
            for (int kf = 0; kf < 4; ++kf)
#pragma unroll
                for (int r = 0; r < 4; ++r) {
                    float v = sacc[kf][qf][r] * SCL;
                    if (masked) {
                        int kvg = kv0 + kf * 16 + kgrp * 4 + r;
                        if (kvg > qglob) v = -3.0e38f;
                    }
                    sacc[kf][qf][r] = v;
                    mx = fmaxf(mx, v);
                }
            mx = fmaxf(mx, __shfl_xor(mx, 16));
            mx = fmaxf(mx, __shfl_xor(mx, 32));
            const float mnew = fmaxf(mreg[qf], mx);
            const float fs = exp2f(mreg[qf] - mnew);
            mreg[qf] = mnew;
            float rsum = 0.f;
            const int prow = wq + qf * 16 + lane15;
#pragma unroll
            for (int kf = 0; kf < 4; ++kf) {
                ushort pu[4];
#pragma unroll
                for (int r = 0; r < 4; ++r) {
                    float p = exp2f(sacc[kf][qf][r] - mnew);
                    rsum += p;
                    pu[r] = f2b(p);
                }
                uint lo = (uint)pu[0] | ((uint)pu[1] << 16);
                uint hi = (uint)pu[2] | ((uint)pu[3] << 16);
                int kvb = (kf * 32 + kgrp * 8) ^ swz;
                *reinterpret_cast<uint2*>((char*)P_s + prow * 128 + kvb) = make_uint2(lo, hi);
            }
            rsum += __shfl_xor(rsum, 16);
            rsum += __shfl_xor(rsum, 32);
            lreg[qf] = lreg[qf] * fs + rsum;
#pragma unroll
            for (int df = 0; df < 4; ++df) o[df][qf] *= fs;
        }

        // ---- O^T += V^T . P^T ----
#pragma unroll
        for (int ks = 0; ks < 2; ++ks) {
            const int kb = (ks * 64 + kgrp16) ^ swz;
            s16x8 va[4], pb[2];
#pragma unroll
            for (int df = 0; df < 4; ++df) {
                int row = df * 16 + lane15;
                va[df] = *reinterpret_cast<const s16x8*>(Vp + row * 128 + kb);
            }
#pragma unroll
            for (int qf = 0; qf < 2; ++qf) {
                int row = wq + qf * 16 + lane15;
                pb[qf] = *reinterpret_cast<const s16x8*>((const char*)P_s + row * 128 + kb);
            }
#pragma unroll
            for (int df = 0; df < 4; ++df)
#pragma unroll
                for (int qf = 0; qf < 2; ++qf)
                    o[df][qf] = __builtin_amdgcn_mfma_f32_16x16x32_bf16(
                        va[df], pb[qf], o[df][qf], 0, 0, 0);
        }
        buf ^= 1;
    }

    // ---- epilogue: normalize, repack via LDS, coalesced bf16 store ----
#pragma unroll
    for (int qf = 0; qf < 2; ++qf) {
        const float inv = 1.0f / lreg[qf];
        const int row = wq + qf * 16 + lane15;
#pragma unroll
        for (int df = 0; df < 4; ++df) {
            ushort pu[4];
#pragma unroll
            for (int r = 0; r < 4; ++r) pu[r] = f2b(o[df][qf][r] * inv);
            uint lo = (uint)pu[0] | ((uint)pu[1] << 16);
            uint hi = (uint)pu[2] | ((uint)pu[3] << 16);
            int db = (df * 32 + kgrp * 8) ^ ((row & 7) << 4);
            *reinterpret_cast<uint2*>((char*)P_s + row * 128 + db) = make_uint2(lo, hi);
        }
    }
    __syncthreads();
    {
        const int q = tid >> 1, half = tid & 1;
        ushort* orow = aob + ((size_t)(b * TT + q0 + q)) * 1024 + h * 64;
#pragma unroll
        for (int j = 0; j < 4; ++j) {
            int db = half * 64 + j * 16;
            int phys = db ^ ((q & 7) << 4);
            s16x8 vv = *reinterpret_cast<const s16x8*>((const char*)P_s + q * 128 + phys);
            *reinterpret_cast<s16x8*>(orow + (db >> 1)) = vv;
        }
    }
#undef STAGE_KV
}

// ---------------------------------------------------------------------------
// Proj GEMM bf16 MFMA: ao[8192x1024] @ Wp[1024x1024] + bias -> f32 out
// ---------------------------------------------------------------------------
__global__ __launch_bounds__(256, 2) void proj_gemm_kernel(
    const ushort* __restrict__ ab,    // [8192][1024] bf16
    const ushort* __restrict__ wpt,   // [1024][1024] bf16 (W^T)
    const float* __restrict__ bias,   // [1024]
    float* __restrict__ out)          // [8192][1024] f32
{
    __shared__ ushort As[2][8192];
    __shared__ ushort Bs[2][8192];

    const int tid = threadIdx.x;
    const int lane = tid & 63, wid = tid >> 6;
    const int lane15 = lane & 15, kgrp = lane >> 4;
    const int wr = wid >> 1, wc = wid & 1;
    const int m0 = blockIdx.y * 128, n0 = blockIdx.x * 128;
    const int swz = (lane15 & 7) << 4;
    const int srcsw = ((lane & 7) ^ ((lane >> 3) & 7)) * 8;
    const int kgrp16 = kgrp * 16;

    f32x4 acc[4][4] = {};

#define STAGE_PRJ(bufi, kofs)                                                     \
    do {                                                                          \
        _Pragma("unroll")                                                         \
        for (int i_ = 0; i_ < 4; ++i_) {                                          \
            int c_ = wid * 4 + i_;                                                \
            gload16(ab + (size_t)(m0 + c_ * 8 + (lane >> 3)) * 1024 + (kofs) + srcsw, \
                    &As[bufi][c_ * 512]);                                         \
            gload16(wpt + (size_t)(n0 + c_ * 8 + (lane >> 3)) * 1024 + (kofs) + srcsw, \
                    &Bs[bufi][c_ * 512]);                                         \
        }                                                                         \
    } while (0)

    STAGE_PRJ(0, 0);
    int buf = 0;
    for (int kt = 0; kt < 16; ++kt) {
        __syncthreads();
        if (kt < 15) STAGE_PRJ(buf ^ 1, (kt + 1) * 64);
        const char* Ap = (const char*)As[buf];
        const char* Bp = (const char*)Bs[buf];
#pragma unroll
        for (int ks = 0; ks < 2; ++ks) {
            s16x8 af[4], bfv[4];
            const int kb = (ks * 64 + kgrp16) ^ swz;
#pragma unroll
            for (int f = 0; f < 4; ++f) {
                int row = wr * 64 + f * 16 + lane15;
                af[f] = *reinterpret_cast<const s16x8*>(Ap + row * 128 + kb);
            }
#pragma unroll
            for (int g = 0; g < 4; ++g) {
                int row = wc * 64 + g * 16 + lane15;
                bfv[g] = *reinterpret_cast<const s16x8*>(Bp + row * 128 + kb);
            }
#pragma unroll
            for (int f = 0; f < 4; ++f)
#pragma unroll
                for (int g = 0; g < 4; ++g)
                    acc[f][g] = __builtin_amdgcn_mfma_f32_16x16x32_bf16(
                        af[f], bfv[g], acc[f][g], 0, 0, 0);
        }
        buf ^= 1;
    }

#pragma unroll
    for (int g = 0; g < 4; ++g) {
        const int n = n0 + wc * 64 + g * 16 + lane15;
        const float bv = bias[n];
#pragma unroll
        for (int f = 0; f < 4; ++f)
#pragma unroll
            for (int r = 0; r < 4; ++r) {
                const int m = m0 + wr * 64 + f * 16 + kgrp * 4 + r;
                out[(size_t)m * 1024 + n] = acc[f][g][r] + bv;
            }
    }
#undef STAGE_PRJ
}

// ---------------------------------------------------------------------------
extern "C" void kernel_launch(void* const* d_in, const int* in_sizes, int n_in,
                              void* d_out, int out_size, void* d_ws, size_t ws_size,
                              hipStream_t stream) {
    const float* x  = (const float*)d_in[0];   // [4,2048,1024]
    const float* Wa = (const float*)d_in[1];   // [1024,3072]
    const float* ba = (const float*)d_in[2];   // [3072]
    const float* Wp = (const float*)d_in[3];   // [1024,1024]
    const float* bp = (const float*)d_in[4];   // [1024]
    float* out = (float*)d_out;                // [4,2048,1024]

    // workspace (byte offsets)
    char* ws = (char*)d_ws;
    ushort* xb  = (ushort*)(ws + 0);            // 16.8 MB  [8192][1024]
    ushort* wat = (ushort*)(ws + 16777216);     // 6.3 MB   [3072][1024]
    ushort* wpt = (ushort*)(ws + 23068672);     // 2.1 MB   [1024][1024]
    ushort* qg  = (ushort*)(ws + 25165824);     // 16.8 MB  [bh][2048][64]
    ushort* kg  = (ushort*)(ws + 41943040);     // 16.8 MB
    ushort* vg  = (ushort*)(ws + 58720256);     // 16.8 MB
    ushort* vtg = (ushort*)(ws + 75497472);     // 16.8 MB  [bh][64][2048]
    ushort* aob = (ushort*)(ws + 92274688);     // 16.8 MB  [8192][1024]
    float2* cs  = (float2*)(ws + 109051904);    // 0.5 MB

    rope_table_kernel<<<dim3(256), dim3(256), 0, stream>>>(cs);
    convert_f32_bf16<<<dim3(4096), dim3(256), 0, stream>>>(x, xb);
    transpose_f32_bf16<<<dim3(48, 16), dim3(256), 0, stream>>>(Wa, wat, 1024, 3072);
    transpose_f32_bf16<<<dim3(16, 16), dim3(256), 0, stream>>>(Wp, wpt, 1024, 1024);
    qkv_gemm_kernel<<<dim3(24, 64), dim3(256), 0, stream>>>(xb, wat, ba, cs, qg, kg, vg);
    transpose_v_kernel<<<dim3(32, 64), dim3(256), 0, stream>>>(vg, vtg);
    flash_kernel<<<dim3(16, 16, 4), dim3(256), 0, stream>>>(qg, kg, vtg, aob);
    proj_gemm_kernel<<<dim3(8, 64), dim3(256), 0, stream>>>(aob, wpt, bp, out);
}

// Round 4
// 276.483 us; speedup vs baseline: 8.4653x; 1.5004x over previous
//
#include <hip/hip_runtime.h>
#include <hip/hip_bf16.h>
#include <math.h>

// (B,T,E,H) = (4,2048,1024,16), D=64
#define TT 2048
#define HH 16

typedef short s16x8 __attribute__((ext_vector_type(8)));
typedef float f32x4 __attribute__((ext_vector_type(4)));

#define F4(p) (*reinterpret_cast<const float4*>(p))

__device__ __forceinline__ void gload16(const void* g, void* l) {
    __builtin_amdgcn_global_load_lds(
        (const __attribute__((address_space(1))) void*)g,
        (__attribute__((address_space(3))) void*)l, 16, 0, 0);
}

__device__ __forceinline__ ushort bf1(float a) {
    __hip_bfloat16 h = __float2bfloat16(a);
    union { __hip_bfloat16 h1; ushort u; } c; c.h1 = h; return c.u;
}
__device__ __forceinline__ uint pack_bf2(float a, float b) {
    __hip_bfloat162 h = __float22bfloat162_rn(make_float2(a, b));
    union { __hip_bfloat162 h2; uint u; } c; c.h2 = h; return c.u;
}

// ---------------------------------------------------------------------------
// RoPE cos/sin table [2048][32] float2
// ---------------------------------------------------------------------------
__global__ void rope_table_kernel(float2* __restrict__ cs) {
    int idx = blockIdx.x * 256 + threadIdx.x;      // 0..65535
    int t = idx >> 5;
    int i = idx & 31;
    double inv_d = exp(((double)(-2 * i) / 64.0) * log(10000.0));
    float invf = (float)inv_d;
    float freq = (float)t * invf;
    double df = (double)freq;
    cs[idx] = make_float2((float)cos(df), (float)sin(df));
}

// ---------------------------------------------------------------------------
// f32 -> bf16 convert (8 elems/thread)
// ---------------------------------------------------------------------------
__global__ __launch_bounds__(256) void convert_f32_bf16(const float* __restrict__ in,
                                                        ushort* __restrict__ out) {
    size_t i = (size_t)(blockIdx.x * 256 + threadIdx.x) * 8;
    float4 a = F4(&in[i]); float4 b = F4(&in[i + 4]);
    s16x8 v;
    v[0] = bf1(a.x); v[1] = bf1(a.y); v[2] = bf1(a.z); v[3] = bf1(a.w);
    v[4] = bf1(b.x); v[5] = bf1(b.y); v[6] = bf1(b.z); v[7] = bf1(b.w);
    *reinterpret_cast<s16x8*>(&out[i]) = v;
}

// ---------------------------------------------------------------------------
// f32 [R][C] -> bf16 [C][R] transpose (64x64 tiles)
// ---------------------------------------------------------------------------
__global__ __launch_bounds__(256) void transpose_f32_bf16(const float* __restrict__ in,
                                                          ushort* __restrict__ out,
                                                          int R, int C) {
    __shared__ float t[64][65];
    int r0 = blockIdx.y * 64, c0 = blockIdx.x * 64;
    int ix = threadIdx.x & 15, iy = threadIdx.x >> 4;
#pragma unroll
    for (int j = 0; j < 4; ++j) {
        float4 v = F4(&in[(size_t)(r0 + iy + j * 16) * C + c0 + ix * 4]);
        t[iy + j * 16][ix * 4 + 0] = v.x;
        t[iy + j * 16][ix * 4 + 1] = v.y;
        t[iy + j * 16][ix * 4 + 2] = v.z;
        t[iy + j * 16][ix * 4 + 3] = v.w;
    }
    __syncthreads();
    int oc = threadIdx.x >> 2, seg = threadIdx.x & 3;
    s16x8 u0, u1;
#pragma unroll
    for (int i = 0; i < 8; ++i) u0[i] = bf1(t[seg * 16 + i][oc]);
#pragma unroll
    for (int i = 0; i < 8; ++i) u1[i] = bf1(t[seg * 16 + 8 + i][oc]);
    ushort* dst = &out[(size_t)(c0 + oc) * R + r0 + seg * 16];
    *reinterpret_cast<s16x8*>(dst) = u0;
    *reinterpret_cast<s16x8*>(dst + 8) = u1;
}

// ---------------------------------------------------------------------------
// QKV GEMM bf16 MFMA + bias + RoPE. q pre-scaled by 0.125*log2(e).
// Outputs: q,k [bh][2048 t][64 d] bf16; v TRANSPOSED [bh][64 d][2048 t] bf16.
// BM=BN=128, BK=64, 256 thr (4 waves), dbuf LDS, XOR swizzle.
// ---------------------------------------------------------------------------
__global__ __launch_bounds__(256, 2) void qkv_gemm_kernel(
    const ushort* __restrict__ xb,    // [8192][1024] bf16
    const ushort* __restrict__ wat,   // [3072][1024] bf16 (W^T)
    const float* __restrict__ bias,   // [3072]
    const float2* __restrict__ cs,    // [2048][32]
    ushort* __restrict__ qg, ushort* __restrict__ kg, ushort* __restrict__ vt)
{
    __shared__ ushort As[2][8192];   // [128 m][64 k]
    __shared__ ushort Bs[2][8192];   // [128 n][64 k]

    const int tid = threadIdx.x;
    const int lane = tid & 63, wid = tid >> 6;
    const int lane15 = lane & 15, kgrp = lane >> 4;
    const int wr = wid >> 1, wc = wid & 1;
    const int m0 = blockIdx.y * 128, n0 = blockIdx.x * 128;
    const int swz = (lane15 & 7) << 4;
    const int srcsw = ((lane & 7) ^ ((lane >> 3) & 7)) * 8;
    const int kgrp16 = kgrp * 16;
    const float SCL = 0.125f * 1.44269504088896f;

    f32x4 acc[4][4] = {};

#define STAGE_QKV(bufi, kofs)                                                     \
    do {                                                                          \
        _Pragma("unroll")                                                         \
        for (int i_ = 0; i_ < 4; ++i_) {                                          \
            int c_ = wid * 4 + i_;                                                \
            gload16(xb + (size_t)(m0 + c_ * 8 + (lane >> 3)) * 1024 + (kofs) + srcsw, \
                    &As[bufi][c_ * 512]);                                         \
            gload16(wat + (size_t)(n0 + c_ * 8 + (lane >> 3)) * 1024 + (kofs) + srcsw, \
                    &Bs[bufi][c_ * 512]);                                         \
        }                                                                         \
    } while (0)

    STAGE_QKV(0, 0);
    int buf = 0;
    for (int kt = 0; kt < 16; ++kt) {
        __syncthreads();
        if (kt < 15) STAGE_QKV(buf ^ 1, (kt + 1) * 64);
        const char* Ap = (const char*)As[buf];
        const char* Bp = (const char*)Bs[buf];
#pragma unroll
        for (int ks = 0; ks < 2; ++ks) {
            s16x8 af[4], bfv[4];
            const int kb = (ks * 64 + kgrp16) ^ swz;
#pragma unroll
            for (int f = 0; f < 4; ++f) {
                int row = wr * 64 + f * 16 + lane15;
                af[f] = *reinterpret_cast<const s16x8*>(Ap + row * 128 + kb);
            }
#pragma unroll
            for (int g = 0; g < 4; ++g) {
                int row = wc * 64 + g * 16 + lane15;
                bfv[g] = *reinterpret_cast<const s16x8*>(Bp + row * 128 + kb);
            }
            __builtin_amdgcn_s_setprio(1);
#pragma unroll
            for (int f = 0; f < 4; ++f)
#pragma unroll
                for (int g = 0; g < 4; ++g)
                    acc[f][g] = __builtin_amdgcn_mfma_f32_16x16x32_bf16(
                        af[f], bfv[g], acc[f][g], 0, 0, 0);
            __builtin_amdgcn_s_setprio(0);
        }
        buf ^= 1;
    }

    // epilogue: bias + rope(q,k) + scatter
#pragma unroll
    for (int g = 0; g < 4; ++g) {
        const int n = n0 + wc * 64 + g * 16 + lane15;
        const int sec = n >> 10;
        const int e = n & 1023;
        const int hh = e >> 6, d = e & 63;
        const float bsv = bias[n];
#pragma unroll
        for (int f = 0; f < 4; ++f) {
            const int mb = m0 + wr * 64 + f * 16 + kgrp * 4;
            const int bb = mb >> 11;
            const int t0 = mb & 2047;
            if (sec == 2) {
                float v0 = acc[f][g][0] + bsv, v1 = acc[f][g][1] + bsv;
                float v2 = acc[f][g][2] + bsv, v3 = acc[f][g][3] + bsv;
                uint2 u = make_uint2(pack_bf2(v0, v1), pack_bf2(v2, v3));
                *reinterpret_cast<uint2*>(
                    &vt[((size_t)(bb * HH + hh) * 64 + d) * TT + t0]) = u;
            } else {
                ushort* dst = (sec == 0) ? qg : kg;
#pragma unroll
                for (int r = 0; r < 4; ++r) {
                    float v = acc[f][g][r] + bsv;
                    float p = __shfl_xor(v, 1);
                    float2 c2 = cs[(t0 + r) * 32 + (d >> 1)];
                    float rv = (d & 1) ? (p * c2.y + v * c2.x) : (v * c2.x - p * c2.y);
                    if (sec == 0) rv *= SCL;
                    dst[((size_t)(bb * HH + hh) * TT + t0 + r) * 64 + d] = bf1(rv);
                }
            }
        }
    }
#undef STAGE_QKV
}

// ---------------------------------------------------------------------------
// Flash attention bf16 MFMA. 512 thr (8 waves x 16 q-rows), q-tile 128,
// kv-tile 64 double-buffered. S^T = mfma(K,Q^T); in-lane online softmax
// (defer-max THR=8); O^T = mfma(V^T,P^T). 64KB LDS -> 2 blocks/CU.
// Grid: 1024 blocks sorted work-descending.
// ---------------------------------------------------------------------------
__global__ __launch_bounds__(512, 4) void flash_kernel(
    const ushort* __restrict__ qg, const ushort* __restrict__ kg,
    const ushort* __restrict__ vt, ushort* __restrict__ aob)
{
    __shared__ ushort Q_s[8192];      // [128 q][64 d]
    __shared__ ushort K_s[2][4096];   // [64 kv][64 d]
    __shared__ ushort V_s[2][4096];   // [64 d][64 kv]
    __shared__ ushort P_s[8192];      // [128 q][64 kv]; reused for output

    const int tid = threadIdx.x;
    const int lane = tid & 63, wid = tid >> 6;
    const int lane15 = lane & 15, kgrp = lane >> 4;
    const int j = blockIdx.x;
    const int qt = 15 - (j >> 6);               // work-descending
    const int bh = j & 63;
    const int b = bh >> 4, h = bh & 15;
    const int q0 = qt * 128;
    const int wq = wid * 16;
    const int wq_abs = q0 + wq;
    const int swz = (lane15 & 7) << 4;
    const int srcsw = ((lane & 7) ^ ((lane >> 3) & 7)) * 8;
    const int kgrp16 = kgrp * 16;
    const int nt = 2 * qt + 2;

    const ushort* qp = qg + (size_t)bh * TT * 64;
    const ushort* kp = kg + (size_t)bh * TT * 64;
    const ushort* vp = vt + (size_t)bh * 64 * TT;

#define STAGE_KV(bufi, kv0_)                                                      \
    do {                                                                          \
        gload16(kp + (size_t)((kv0_) + wid * 8 + (lane >> 3)) * 64 + srcsw,       \
                &K_s[bufi][wid * 512]);                                           \
        gload16(vp + (size_t)(wid * 8 + (lane >> 3)) * TT + (kv0_) + srcsw,       \
                &V_s[bufi][wid * 512]);                                           \
    } while (0)

    // stage Q (once) + first KV tile
#pragma unroll
    for (int i = 0; i < 2; ++i) {
        int c = wid * 2 + i;
        gload16(qp + (size_t)(q0 + c * 8 + (lane >> 3)) * 64 + srcsw, &Q_s[c * 512]);
    }
    STAGE_KV(0, 0);

    f32x4 o[4] = {};
    float mreg = -3.0e38f;
    float lreg = 0.f;

    int buf = 0;
    for (int t = 0; t < nt; ++t) {
        __syncthreads();                         // staged tile landed (vmcnt0)
        if (t + 1 < nt) STAGE_KV(buf ^ 1, (t + 1) * 64);

        const int kv0 = t * 64;
        if (kv0 <= wq_abs + 15) {                // skip fully-masked tiles
            const char* Kp = (const char*)K_s[buf];
            const char* Vp = (const char*)V_s[buf];

            // ---- S^T = K . Q^T ----
            f32x4 sacc[4] = {};
#pragma unroll
            for (int ks = 0; ks < 2; ++ks) {
                const int kb = (ks * 64 + kgrp16) ^ swz;
                s16x8 ka[4], qb;
#pragma unroll
                for (int kf = 0; kf < 4; ++kf)
                    ka[kf] = *reinterpret_cast<const s16x8*>(Kp + (kf * 16 + lane15) * 128 + kb);
                qb = *reinterpret_cast<const s16x8*>((const char*)Q_s + (wq + lane15) * 128 + kb);
                __builtin_amdgcn_s_setprio(1);
#pragma unroll
                for (int kf = 0; kf < 4; ++kf)
                    sacc[kf] = __builtin_amdgcn_mfma_f32_16x16x32_bf16(
                        ka[kf], qb, sacc[kf], 0, 0, 0);
                __builtin_amdgcn_s_setprio(0);
            }

            // ---- online softmax (per lane: 16 kv values, one q col) ----
            const int qglob = q0 + wq + lane15;
            const bool masked = (kv0 + 63 > wq_abs);
            float mx = -3.0e38f;
            if (masked) {
#pragma unroll
                for (int kf = 0; kf < 4; ++kf)
#pragma unroll
                    for (int r = 0; r < 4; ++r) {
                        int kvg = kv0 + kf * 16 + kgrp * 4 + r;
                        float v = (kvg > qglob) ? -3.0e38f : sacc[kf][r];
                        sacc[kf][r] = v;
                        mx = fmaxf(mx, v);
                    }
            } else {
#pragma unroll
                for (int kf = 0; kf < 4; ++kf)
#pragma unroll
                    for (int r = 0; r < 4; ++r) mx = fmaxf(mx, sacc[kf][r]);
            }
            mx = fmaxf(mx, __shfl_xor(mx, 16));
            mx = fmaxf(mx, __shfl_xor(mx, 32));
            if (!__all(mx <= mreg + 8.f)) {      // defer-max rescale
                const float mnew = fmaxf(mreg, mx);
                const float fs = exp2f(mreg - mnew);
                lreg *= fs;
#pragma unroll
                for (int df = 0; df < 4; ++df) o[df] *= fs;
                mreg = mnew;
            }
            float rsum = 0.f;
            const int prow = wq + lane15;
#pragma unroll
            for (int kf = 0; kf < 4; ++kf) {
                float p0 = exp2f(sacc[kf][0] - mreg);
                float p1 = exp2f(sacc[kf][1] - mreg);
                float p2 = exp2f(sacc[kf][2] - mreg);
                float p3 = exp2f(sacc[kf][3] - mreg);
                rsum += (p0 + p1) + (p2 + p3);
                uint2 u = make_uint2(pack_bf2(p0, p1), pack_bf2(p2, p3));
                int kvb = (kf * 32 + kgrp * 8) ^ swz;
                *reinterpret_cast<uint2*>((char*)P_s + prow * 128 + kvb) = u;
            }
            rsum += __shfl_xor(rsum, 16);
            rsum += __shfl_xor(rsum, 32);
            lreg += rsum;

            // ---- O^T += V^T . P^T ----
#pragma unroll
            for (int ks = 0; ks < 2; ++ks) {
                const int kb = (ks * 64 + kgrp16) ^ swz;
                s16x8 va[4], pb;
#pragma unroll
                for (int df = 0; df < 4; ++df)
                    va[df] = *reinterpret_cast<const s16x8*>(Vp + (df * 16 + lane15) * 128 + kb);
                pb = *reinterpret_cast<const s16x8*>((const char*)P_s + (wq + lane15) * 128 + kb);
                __builtin_amdgcn_s_setprio(1);
#pragma unroll
                for (int df = 0; df < 4; ++df)
                    o[df] = __builtin_amdgcn_mfma_f32_16x16x32_bf16(
                        va[df], pb, o[df], 0, 0, 0);
                __builtin_amdgcn_s_setprio(0);
            }
        }
        buf ^= 1;
    }

    // ---- epilogue: normalize, repack via P_s, coalesced bf16 store ----
    {
        const float inv = 1.0f / lreg;
        const int row = wq + lane15;
#pragma unroll
        for (int df = 0; df < 4; ++df) {
            float p0 = o[df][0] * inv, p1 = o[df][1] * inv;
            float p2 = o[df][2] * inv, p3 = o[df][3] * inv;
            uint2 u = make_uint2(pack_bf2(p0, p1), pack_bf2(p2, p3));
            int db = (df * 32 + kgrp * 8) ^ ((row & 7) << 4);
            *reinterpret_cast<uint2*>((char*)P_s + row * 128 + db) = u;
        }
    }
    __syncthreads();
    {
        const int q = tid >> 2, seg = tid & 3;
        ushort* orow = aob + ((size_t)(b * TT + q0 + q)) * 1024 + h * 64 + seg * 16;
        int p0 = (seg * 32) ^ ((q & 7) << 4);
        int p1 = (seg * 32 + 16) ^ ((q & 7) << 4);
        s16x8 v0 = *reinterpret_cast<const s16x8*>((const char*)P_s + q * 128 + p0);
        s16x8 v1 = *reinterpret_cast<const s16x8*>((const char*)P_s + q * 128 + p1);
        *reinterpret_cast<s16x8*>(orow) = v0;
        *reinterpret_cast<s16x8*>(orow + 8) = v1;
    }
#undef STAGE_KV
}

// ---------------------------------------------------------------------------
// Proj GEMM bf16 MFMA: ao[8192x1024] @ Wp[1024x1024] + bias -> f32 out
// ---------------------------------------------------------------------------
__global__ __launch_bounds__(256, 2) void proj_gemm_kernel(
    const ushort* __restrict__ ab,    // [8192][1024] bf16
    const ushort* __restrict__ wpt,   // [1024][1024] bf16 (W^T)
    const float* __restrict__ bias,   // [1024]
    float* __restrict__ out)          // [8192][1024] f32
{
    __shared__ ushort As[2][8192];
    __shared__ ushort Bs[2][8192];

    const int tid = threadIdx.x;
    const int lane = tid & 63, wid = tid >> 6;
    const int lane15 = lane & 15, kgrp = lane >> 4;
    const int wr = wid >> 1, wc = wid & 1;
    const int m0 = blockIdx.y * 128, n0 = blockIdx.x * 128;
    const int swz = (lane15 & 7) << 4;
    const int srcsw = ((lane & 7) ^ ((lane >> 3) & 7)) * 8;
    const int kgrp16 = kgrp * 16;

    f32x4 acc[4][4] = {};

#define STAGE_PRJ(bufi, kofs)                                                     \
    do {                                                                          \
        _Pragma("unroll")                                                         \
        for (int i_ = 0; i_ < 4; ++i_) {                                          \
            int c_ = wid * 4 + i_;                                                \
            gload16(ab + (size_t)(m0 + c_ * 8 + (lane >> 3)) * 1024 + (kofs) + srcsw, \
                    &As[bufi][c_ * 512]);                                         \
            gload16(wpt + (size_t)(n0 + c_ * 8 + (lane >> 3)) * 1024 + (kofs) + srcsw, \
                    &Bs[bufi][c_ * 512]);                                         \
        }                                                                         \
    } while (0)

    STAGE_PRJ(0, 0);
    int buf = 0;
    for (int kt = 0; kt < 16; ++kt) {
        __syncthreads();
        if (kt < 15) STAGE_PRJ(buf ^ 1, (kt + 1) * 64);
        const char* Ap = (const char*)As[buf];
        const char* Bp = (const char*)Bs[buf];
#pragma unroll
        for (int ks = 0; ks < 2; ++ks) {
            s16x8 af[4], bfv[4];
            const int kb = (ks * 64 + kgrp16) ^ swz;
#pragma unroll
            for (int f = 0; f < 4; ++f) {
                int row = wr * 64 + f * 16 + lane15;
                af[f] = *reinterpret_cast<const s16x8*>(Ap + row * 128 + kb);
            }
#pragma unroll
            for (int g = 0; g < 4; ++g) {
                int row = wc * 64 + g * 16 + lane15;
                bfv[g] = *reinterpret_cast<const s16x8*>(Bp + row * 128 + kb);
            }
            __builtin_amdgcn_s_setprio(1);
#pragma unroll
            for (int f = 0; f < 4; ++f)
#pragma unroll
                for (int g = 0; g < 4; ++g)
                    acc[f][g] = __builtin_amdgcn_mfma_f32_16x16x32_bf16(
                        af[f], bfv[g], acc[f][g], 0, 0, 0);
            __builtin_amdgcn_s_setprio(0);
        }
        buf ^= 1;
    }

#pragma unroll
    for (int g = 0; g < 4; ++g) {
        const int n = n0 + wc * 64 + g * 16 + lane15;
        const float bv = bias[n];
#pragma unroll
        for (int f = 0; f < 4; ++f)
#pragma unroll
            for (int r = 0; r < 4; ++r) {
                const int m = m0 + wr * 64 + f * 16 + kgrp * 4 + r;
                out[(size_t)m * 1024 + n] = acc[f][g][r] + bv;
            }
    }
#undef STAGE_PRJ
}

// ---------------------------------------------------------------------------
extern "C" void kernel_launch(void* const* d_in, const int* in_sizes, int n_in,
                              void* d_out, int out_size, void* d_ws, size_t ws_size,
                              hipStream_t stream) {
    const float* x  = (const float*)d_in[0];   // [4,2048,1024]
    const float* Wa = (const float*)d_in[1];   // [1024,3072]
    const float* ba = (const float*)d_in[2];   // [3072]
    const float* Wp = (const float*)d_in[3];   // [1024,1024]
    const float* bp = (const float*)d_in[4];   // [1024]
    float* out = (float*)d_out;                // [4,2048,1024]

    // workspace (byte offsets)
    char* ws = (char*)d_ws;
    ushort* xb  = (ushort*)(ws + 0);            // 16.8 MB  [8192][1024]
    ushort* wat = (ushort*)(ws + 16777216);     // 6.3 MB   [3072][1024]
    ushort* wpt = (ushort*)(ws + 23068672);     // 2.1 MB   [1024][1024]
    ushort* qg  = (ushort*)(ws + 25165824);     // 16.8 MB  [bh][2048][64]
    ushort* kg  = (ushort*)(ws + 41943040);     // 16.8 MB  [bh][2048][64]
    ushort* vtg = (ushort*)(ws + 58720256);     // 16.8 MB  [bh][64][2048]
    ushort* aob = (ushort*)(ws + 75497472);     // 16.8 MB  [8192][1024]
    float2* cs  = (float2*)(ws + 92274688);     // 0.5 MB

    rope_table_kernel<<<dim3(256), dim3(256), 0, stream>>>(cs);
    convert_f32_bf16<<<dim3(4096), dim3(256), 0, stream>>>(x, xb);
    transpose_f32_bf16<<<dim3(48, 16), dim3(256), 0, stream>>>(Wa, wat, 1024, 3072);
    transpose_f32_bf16<<<dim3(16, 16), dim3(256), 0, stream>>>(Wp, wpt, 1024, 1024);
    qkv_gemm_kernel<<<dim3(24, 64), dim3(256), 0, stream>>>(xb, wat, ba, cs, qg, kg, vtg);
    flash_kernel<<<dim3(1024), dim3(512), 0, stream>>>(qg, kg, vtg, aob);
    proj_gemm_kernel<<<dim3(8, 64), dim3(256), 0, stream>>>(aob, Wp != nullptr ? wpt : wpt, bp, out);
}

// Round 5
// 270.297 us; speedup vs baseline: 8.6591x; 1.0229x over previous
//
#include <hip/hip_runtime.h>
#include <hip/hip_bf16.h>
#include <math.h>

// (B,T,E,H) = (4,2048,1024,16), D=64
#define TT 2048
#define HH 16

typedef short s16x8 __attribute__((ext_vector_type(8)));
typedef float f32x4 __attribute__((ext_vector_type(4)));

#define F4(p) (*reinterpret_cast<const float4*>(p))

__device__ __forceinline__ void gload16(const void* g, void* l) {
    __builtin_amdgcn_global_load_lds(
        (const __attribute__((address_space(1))) void*)g,
        (__attribute__((address_space(3))) void*)l, 16, 0, 0);
}

__device__ __forceinline__ ushort bf1(float a) {
    __hip_bfloat16 h = __float2bfloat16(a);
    union { __hip_bfloat16 h1; ushort u; } c; c.h1 = h; return c.u;
}
__device__ __forceinline__ uint pack_bf2(float a, float b) {
    __hip_bfloat162 h = __float22bfloat162_rn(make_float2(a, b));
    union { __hip_bfloat162 h2; uint u; } c; c.h2 = h; return c.u;
}

// ---------------------------------------------------------------------------
// Prep kernel (fused): rope table | x->bf16 | W_attn^T bf16 | W_proj^T bf16
// Block ranges: [0,256) rope, [256,4352) convert, [4352,5120) Wa, [5120,5376) Wp
// ---------------------------------------------------------------------------
__global__ __launch_bounds__(256) void prep_kernel(
    const float* __restrict__ x, const float* __restrict__ Wa,
    const float* __restrict__ Wp, ushort* __restrict__ xb,
    ushort* __restrict__ wat, ushort* __restrict__ wpt, float2* __restrict__ cs)
{
    __shared__ float tsh[64][65];
    const int blk = blockIdx.x;
    const int tid = threadIdx.x;

    if (blk < 256) {
        // ---- rope cos/sin table [2048][32] ----
        int idx = blk * 256 + tid;
        int t = idx >> 5;
        int i = idx & 31;
        double inv_d = exp(((double)(-2 * i) / 64.0) * log(10000.0));
        float invf = (float)inv_d;
        float freq = (float)t * invf;
        double df = (double)freq;
        cs[idx] = make_float2((float)cos(df), (float)sin(df));
    } else if (blk < 4352) {
        // ---- convert x f32 -> bf16, 8 elems/thread ----
        size_t i = (size_t)(blk - 256) * 2048 + (size_t)tid * 8;
        float4 a = F4(&x[i]); float4 b = F4(&x[i + 4]);
        s16x8 v;
        v[0] = bf1(a.x); v[1] = bf1(a.y); v[2] = bf1(a.z); v[3] = bf1(a.w);
        v[4] = bf1(b.x); v[5] = bf1(b.y); v[6] = bf1(b.z); v[7] = bf1(b.w);
        *reinterpret_cast<s16x8*>(&xb[i]) = v;
    } else {
        // ---- transpose f32 [R][C] -> bf16 [C][R], 64x64 tiles ----
        const float* in; ushort* out; int R, C, bx, by;
        if (blk < 5120) { int r = blk - 4352; in = Wa; out = wat; R = 1024; C = 3072; bx = r % 48; by = r / 48; }
        else            { int r = blk - 5120; in = Wp; out = wpt; R = 1024; C = 1024; bx = r & 15; by = r >> 4; }
        int r0 = by * 64, c0 = bx * 64;
        int ix = tid & 15, iy = tid >> 4;
#pragma unroll
        for (int j = 0; j < 4; ++j) {
            float4 v = F4(&in[(size_t)(r0 + iy + j * 16) * C + c0 + ix * 4]);
            tsh[iy + j * 16][ix * 4 + 0] = v.x;
            tsh[iy + j * 16][ix * 4 + 1] = v.y;
            tsh[iy + j * 16][ix * 4 + 2] = v.z;
            tsh[iy + j * 16][ix * 4 + 3] = v.w;
        }
        __syncthreads();
        int oc = tid >> 2, seg = tid & 3;
        s16x8 u0, u1;
#pragma unroll
        for (int i = 0; i < 8; ++i) u0[i] = bf1(tsh[seg * 16 + i][oc]);
#pragma unroll
        for (int i = 0; i < 8; ++i) u1[i] = bf1(tsh[seg * 16 + 8 + i][oc]);
        ushort* dst = &out[(size_t)(c0 + oc) * R + r0 + seg * 16];
        *reinterpret_cast<s16x8*>(dst) = u0;
        *reinterpret_cast<s16x8*>(dst + 8) = u1;
    }
}

// ---------------------------------------------------------------------------
// QKV GEMM bf16 MFMA + bias + RoPE. q pre-scaled by 0.125*log2(e).
// Outputs: q,k [bh][2048 t][64 d] bf16; v TRANSPOSED [bh][64 d][2048 t] bf16.
// BM=BN=128, BK=64, 256 thr (4 waves), dbuf LDS, XOR swizzle.
// ---------------------------------------------------------------------------
__global__ __launch_bounds__(256, 2) void qkv_gemm_kernel(
    const ushort* __restrict__ xb,    // [8192][1024] bf16
    const ushort* __restrict__ wat,   // [3072][1024] bf16 (W^T)
    const float* __restrict__ bias,   // [3072]
    const float2* __restrict__ cs,    // [2048][32]
    ushort* __restrict__ qg, ushort* __restrict__ kg, ushort* __restrict__ vt)
{
    __shared__ ushort As[2][8192];   // [128 m][64 k]
    __shared__ ushort Bs[2][8192];   // [128 n][64 k]

    const int tid = threadIdx.x;
    const int lane = tid & 63, wid = tid >> 6;
    const int lane15 = lane & 15, kgrp = lane >> 4;
    const int wr = wid >> 1, wc = wid & 1;
    const int m0 = blockIdx.y * 128, n0 = blockIdx.x * 128;
    const int swz = (lane15 & 7) << 4;
    const int srcsw = ((lane & 7) ^ ((lane >> 3) & 7)) * 8;
    const int kgrp16 = kgrp * 16;
    const float SCL = 0.125f * 1.44269504088896f;

    f32x4 acc[4][4] = {};

#define STAGE_QKV(bufi, kofs)                                                     \
    do {                                                                          \
        _Pragma("unroll")                                                         \
        for (int i_ = 0; i_ < 4; ++i_) {                                          \
            int c_ = wid * 4 + i_;                                                \
            gload16(xb + (size_t)(m0 + c_ * 8 + (lane >> 3)) * 1024 + (kofs) + srcsw, \
                    &As[bufi][c_ * 512]);                                         \
            gload16(wat + (size_t)(n0 + c_ * 8 + (lane >> 3)) * 1024 + (kofs) + srcsw, \
                    &Bs[bufi][c_ * 512]);                                         \
        }                                                                         \
    } while (0)

    STAGE_QKV(0, 0);
    int buf = 0;
    for (int kt = 0; kt < 16; ++kt) {
        __syncthreads();
        if (kt < 15) STAGE_QKV(buf ^ 1, (kt + 1) * 64);
        const char* Ap = (const char*)As[buf];
        const char* Bp = (const char*)Bs[buf];
#pragma unroll
        for (int ks = 0; ks < 2; ++ks) {
            s16x8 af[4], bfv[4];
            const int kb = (ks * 64 + kgrp16) ^ swz;
#pragma unroll
            for (int f = 0; f < 4; ++f) {
                int row = wr * 64 + f * 16 + lane15;
                af[f] = *reinterpret_cast<const s16x8*>(Ap + row * 128 + kb);
            }
#pragma unroll
            for (int g = 0; g < 4; ++g) {
                int row = wc * 64 + g * 16 + lane15;
                bfv[g] = *reinterpret_cast<const s16x8*>(Bp + row * 128 + kb);
            }
            __builtin_amdgcn_s_setprio(1);
#pragma unroll
            for (int f = 0; f < 4; ++f)
#pragma unroll
                for (int g = 0; g < 4; ++g)
                    acc[f][g] = __builtin_amdgcn_mfma_f32_16x16x32_bf16(
                        af[f], bfv[g], acc[f][g], 0, 0, 0);
            __builtin_amdgcn_s_setprio(0);
        }
        buf ^= 1;
    }

    // epilogue: bias + rope(q,k) + scatter
#pragma unroll
    for (int g = 0; g < 4; ++g) {
        const int n = n0 + wc * 64 + g * 16 + lane15;
        const int sec = n >> 10;
        const int e = n & 1023;
        const int hh = e >> 6, d = e & 63;
        const float bsv = bias[n];
#pragma unroll
        for (int f = 0; f < 4; ++f) {
            const int mb = m0 + wr * 64 + f * 16 + kgrp * 4;
            const int bb = mb >> 11;
            const int t0 = mb & 2047;
            if (sec == 2) {
                float v0 = acc[f][g][0] + bsv, v1 = acc[f][g][1] + bsv;
                float v2 = acc[f][g][2] + bsv, v3 = acc[f][g][3] + bsv;
                uint2 u = make_uint2(pack_bf2(v0, v1), pack_bf2(v2, v3));
                *reinterpret_cast<uint2*>(
                    &vt[((size_t)(bb * HH + hh) * 64 + d) * TT + t0]) = u;
            } else {
                ushort* dst = (sec == 0) ? qg : kg;
#pragma unroll
                for (int r = 0; r < 4; ++r) {
                    float v = acc[f][g][r] + bsv;
                    float p = __shfl_xor(v, 1);
                    float2 c2 = cs[(t0 + r) * 32 + (d >> 1)];
                    float rv = (d & 1) ? (p * c2.y + v * c2.x) : (v * c2.x - p * c2.y);
                    if (sec == 0) rv *= SCL;
                    dst[((size_t)(bb * HH + hh) * TT + t0 + r) * 64 + d] = bf1(rv);
                }
            }
        }
    }
#undef STAGE_QKV
}

// ---------------------------------------------------------------------------
// Flash attention bf16 MFMA. 512 thr (8 waves x 16 q-rows), q-tile 128,
// kv-tile 64 double-buffered. Q in REGISTERS (per-wave fragment); LDS 48KB
// (K/V dbuf + P) -> 3 blocks/CU (6 waves/SIMD). S^T = mfma(K,Q^T); in-lane
// online softmax (defer-max THR=8); O^T = mfma(V^T,P^T).
// Grid: 1024 blocks sorted work-descending.
// ---------------------------------------------------------------------------
__global__ __launch_bounds__(512, 6) void flash_kernel(
    const ushort* __restrict__ qg, const ushort* __restrict__ kg,
    const ushort* __restrict__ vt, ushort* __restrict__ aob)
{
    __shared__ ushort K_s[2][4096];   // [64 kv][64 d]
    __shared__ ushort V_s[2][4096];   // [64 d][64 kv]
    __shared__ ushort P_s[8192];      // [8 waves][16 q][64 kv]; reused as output

    const int tid = threadIdx.x;
    const int lane = tid & 63, wid = tid >> 6;
    const int lane15 = lane & 15, kgrp = lane >> 4;
    const int j = blockIdx.x;
    const int qt = 15 - (j >> 6);               // work-descending
    const int bh = j & 63;
    const int b = bh >> 4, h = bh & 15;
    const int q0 = qt * 128;
    const int wq = wid * 16;
    const int wq_abs = q0 + wq;
    const int swz = (lane15 & 7) << 4;
    const int srcsw = ((lane & 7) ^ ((lane >> 3) & 7)) * 8;
    const int kgrp16 = kgrp * 16;
    const int nt = 2 * qt + 2;

    const ushort* qp = qg + (size_t)bh * TT * 64;
    const ushort* kp = kg + (size_t)bh * TT * 64;
    const ushort* vp = vt + (size_t)bh * 64 * TT;
    char* Pw = (char*)P_s + wid * 2048;          // this wave's 16 P rows

#define STAGE_KV(bufi, kv0_)                                                      \
    do {                                                                          \
        gload16(kp + (size_t)((kv0_) + wid * 8 + (lane >> 3)) * 64 + srcsw,       \
                &K_s[bufi][wid * 512]);                                           \
        gload16(vp + (size_t)(wid * 8 + (lane >> 3)) * TT + (kv0_) + srcsw,       \
                &V_s[bufi][wid * 512]);                                           \
    } while (0)

    // Q fragments straight to registers (this wave's 16 rows)
    const ushort* qrow = qp + (size_t)(q0 + wq + lane15) * 64 + kgrp * 8;
    s16x8 qfr[2];
    qfr[0] = *reinterpret_cast<const s16x8*>(qrow);
    qfr[1] = *reinterpret_cast<const s16x8*>(qrow + 32);

    STAGE_KV(0, 0);

    f32x4 o[4] = {};
    float mreg = -3.0e38f;
    float lreg = 0.f;

    int buf = 0;
    for (int t = 0; t < nt; ++t) {
        __syncthreads();                         // staged tile landed (vmcnt0)
        if (t + 1 < nt) STAGE_KV(buf ^ 1, (t + 1) * 64);

        const int kv0 = t * 64;
        if (kv0 <= wq_abs + 15) {                // skip fully-masked tiles
            const char* Kp = (const char*)K_s[buf];
            const char* Vp = (const char*)V_s[buf];

            // ---- S^T = K . Q^T ----
            f32x4 sacc[4] = {};
#pragma unroll
            for (int ks = 0; ks < 2; ++ks) {
                const int kb = (ks * 64 + kgrp16) ^ swz;
                s16x8 ka[4];
#pragma unroll
                for (int kf = 0; kf < 4; ++kf)
                    ka[kf] = *reinterpret_cast<const s16x8*>(Kp + (kf * 16 + lane15) * 128 + kb);
                __builtin_amdgcn_s_setprio(1);
#pragma unroll
                for (int kf = 0; kf < 4; ++kf)
                    sacc[kf] = __builtin_amdgcn_mfma_f32_16x16x32_bf16(
                        ka[kf], qfr[ks], sacc[kf], 0, 0, 0);
                __builtin_amdgcn_s_setprio(0);
            }

            // ---- online softmax (per lane: 16 kv values, one q col) ----
            const int qglob = q0 + wq + lane15;
            const bool masked = (kv0 + 63 > wq_abs);
            float mx = -3.0e38f;
            if (masked) {
#pragma unroll
                for (int kf = 0; kf < 4; ++kf)
#pragma unroll
                    for (int r = 0; r < 4; ++r) {
                        int kvg = kv0 + kf * 16 + kgrp * 4 + r;
                        float v = (kvg > qglob) ? -3.0e38f : sacc[kf][r];
                        sacc[kf][r] = v;
                        mx = fmaxf(mx, v);
                    }
            } else {
#pragma unroll
                for (int kf = 0; kf < 4; ++kf)
#pragma unroll
                    for (int r = 0; r < 4; ++r) mx = fmaxf(mx, sacc[kf][r]);
            }
            mx = fmaxf(mx, __shfl_xor(mx, 16));
            mx = fmaxf(mx, __shfl_xor(mx, 32));
            if (!__all(mx <= mreg + 8.f)) {      // defer-max rescale
                const float mnew = fmaxf(mreg, mx);
                const float fs = exp2f(mreg - mnew);
                lreg *= fs;
#pragma unroll
                for (int df = 0; df < 4; ++df) o[df] *= fs;
                mreg = mnew;
            }
            float rsum = 0.f;
#pragma unroll
            for (int kf = 0; kf < 4; ++kf) {
                float p0 = exp2f(sacc[kf][0] - mreg);
                float p1 = exp2f(sacc[kf][1] - mreg);
                float p2 = exp2f(sacc[kf][2] - mreg);
                float p3 = exp2f(sacc[kf][3] - mreg);
                rsum += (p0 + p1) + (p2 + p3);
                uint2 u = make_uint2(pack_bf2(p0, p1), pack_bf2(p2, p3));
                int kvb = (kf * 32 + kgrp * 8) ^ swz;
                *reinterpret_cast<uint2*>(Pw + lane15 * 128 + kvb) = u;
            }
            rsum += __shfl_xor(rsum, 16);
            rsum += __shfl_xor(rsum, 32);
            lreg += rsum;

            // ---- O^T += V^T . P^T ----
#pragma unroll
            for (int ks = 0; ks < 2; ++ks) {
                const int kb = (ks * 64 + kgrp16) ^ swz;
                s16x8 va[4], pb;
#pragma unroll
                for (int df = 0; df < 4; ++df)
                    va[df] = *reinterpret_cast<const s16x8*>(Vp + (df * 16 + lane15) * 128 + kb);
                pb = *reinterpret_cast<const s16x8*>(Pw + lane15 * 128 + kb);
                __builtin_amdgcn_s_setprio(1);
#pragma unroll
                for (int df = 0; df < 4; ++df)
                    o[df] = __builtin_amdgcn_mfma_f32_16x16x32_bf16(
                        va[df], pb, o[df], 0, 0, 0);
                __builtin_amdgcn_s_setprio(0);
            }
        }
        buf ^= 1;
    }

    // ---- epilogue: normalize, repack via P_s, coalesced bf16 store ----
    {
        const float inv = 1.0f / lreg;
        const int row = wq + lane15;
#pragma unroll
        for (int df = 0; df < 4; ++df) {
            float p0 = o[df][0] * inv, p1 = o[df][1] * inv;
            float p2 = o[df][2] * inv, p3 = o[df][3] * inv;
            uint2 u = make_uint2(pack_bf2(p0, p1), pack_bf2(p2, p3));
            int db = (df * 32 + kgrp * 8) ^ ((row & 7) << 4);
            *reinterpret_cast<uint2*>((char*)P_s + row * 128 + db) = u;
        }
    }
    __syncthreads();
    {
        const int q = tid >> 2, seg = tid & 3;
        ushort* orow = aob + ((size_t)(b * TT + q0 + q)) * 1024 + h * 64 + seg * 16;
        int p0 = (seg * 32) ^ ((q & 7) << 4);
        int p1 = (seg * 32 + 16) ^ ((q & 7) << 4);
        s16x8 v0 = *reinterpret_cast<const s16x8*>((const char*)P_s + q * 128 + p0);
        s16x8 v1 = *reinterpret_cast<const s16x8*>((const char*)P_s + q * 128 + p1);
        *reinterpret_cast<s16x8*>(orow) = v0;
        *reinterpret_cast<s16x8*>(orow + 8) = v1;
    }
#undef STAGE_KV
}

// ---------------------------------------------------------------------------
// Proj GEMM bf16 MFMA: ao[8192x1024] @ Wp[1024x1024] + bias -> f32 out
// ---------------------------------------------------------------------------
__global__ __launch_bounds__(256, 2) void proj_gemm_kernel(
    const ushort* __restrict__ ab,    // [8192][1024] bf16
    const ushort* __restrict__ wpt,   // [1024][1024] bf16 (W^T)
    const float* __restrict__ bias,   // [1024]
    float* __restrict__ out)          // [8192][1024] f32
{
    __shared__ ushort As[2][8192];
    __shared__ ushort Bs[2][8192];

    const int tid = threadIdx.x;
    const int lane = tid & 63, wid = tid >> 6;
    const int lane15 = lane & 15, kgrp = lane >> 4;
    const int wr = wid >> 1, wc = wid & 1;
    const int m0 = blockIdx.y * 128, n0 = blockIdx.x * 128;
    const int swz = (lane15 & 7) << 4;
    const int srcsw = ((lane & 7) ^ ((lane >> 3) & 7)) * 8;
    const int kgrp16 = kgrp * 16;

    f32x4 acc[4][4] = {};

#define STAGE_PRJ(bufi, kofs)                                                     \
    do {                                                                          \
        _Pragma("unroll")                                                         \
        for (int i_ = 0; i_ < 4; ++i_) {                                          \
            int c_ = wid * 4 + i_;                                                \
            gload16(ab + (size_t)(m0 + c_ * 8 + (lane >> 3)) * 1024 + (kofs) + srcsw, \
                    &As[bufi][c_ * 512]);                                         \
            gload16(wpt + (size_t)(n0 + c_ * 8 + (lane >> 3)) * 1024 + (kofs) + srcsw, \
                    &Bs[bufi][c_ * 512]);                                         \
        }                                                                         \
    } while (0)

    STAGE_PRJ(0, 0);
    int buf = 0;
    for (int kt = 0; kt < 16; ++kt) {
        __syncthreads();
        if (kt < 15) STAGE_PRJ(buf ^ 1, (kt + 1) * 64);
        const char* Ap = (const char*)As[buf];
        const char* Bp = (const char*)Bs[buf];
#pragma unroll
        for (int ks = 0; ks < 2; ++ks) {
            s16x8 af[4], bfv[4];
            const int kb = (ks * 64 + kgrp16) ^ swz;
#pragma unroll
            for (int f = 0; f < 4; ++f) {
                int row = wr * 64 + f * 16 + lane15;
                af[f] = *reinterpret_cast<const s16x8*>(Ap + row * 128 + kb);
            }
#pragma unroll
            for (int g = 0; g < 4; ++g) {
                int row = wc * 64 + g * 16 + lane15;
                bfv[g] = *reinterpret_cast<const s16x8*>(Bp + row * 128 + kb);
            }
            __builtin_amdgcn_s_setprio(1);
#pragma unroll
            for (int f = 0; f < 4; ++f)
#pragma unroll
                for (int g = 0; g < 4; ++g)
                    acc[f][g] = __builtin_amdgcn_mfma_f32_16x16x32_bf16(
                        af[f], bfv[g], acc[f][g], 0, 0, 0);
            __builtin_amdgcn_s_setprio(0);
        }
        buf ^= 1;
    }

#pragma unroll
    for (int g = 0; g < 4; ++g) {
        const int n = n0 + wc * 64 + g * 16 + lane15;
        const float bv = bias[n];
#pragma unroll
        for (int f = 0; f < 4; ++f)
#pragma unroll
            for (int r = 0; r < 4; ++r) {
                const int m = m0 + wr * 64 + f * 16 + kgrp * 4 + r;
                out[(size_t)m * 1024 + n] = acc[f][g][r] + bv;
            }
    }
#undef STAGE_PRJ
}

// ---------------------------------------------------------------------------
extern "C" void kernel_launch(void* const* d_in, const int* in_sizes, int n_in,
                              void* d_out, int out_size, void* d_ws, size_t ws_size,
                              hipStream_t stream) {
    const float* x  = (const float*)d_in[0];   // [4,2048,1024]
    const float* Wa = (const float*)d_in[1];   // [1024,3072]
    const float* ba = (const float*)d_in[2];   // [3072]
    const float* Wp = (const float*)d_in[3];   // [1024,1024]
    const float* bp = (const float*)d_in[4];   // [1024]
    float* out = (float*)d_out;                // [4,2048,1024]

    // workspace (byte offsets)
    char* ws = (char*)d_ws;
    ushort* xb  = (ushort*)(ws + 0);            // 16.8 MB  [8192][1024]
    ushort* wat = (ushort*)(ws + 16777216);     // 6.3 MB   [3072][1024]
    ushort* wpt = (ushort*)(ws + 23068672);     // 2.1 MB   [1024][1024]
    ushort* qg  = (ushort*)(ws + 25165824);     // 16.8 MB  [bh][2048][64]
    ushort* kg  = (ushort*)(ws + 41943040);     // 16.8 MB  [bh][2048][64]
    ushort* vtg = (ushort*)(ws + 58720256);     // 16.8 MB  [bh][64][2048]
    ushort* aob = (ushort*)(ws + 75497472);     // 16.8 MB  [8192][1024]
    float2* cs  = (float2*)(ws + 92274688);     // 0.5 MB

    prep_kernel<<<dim3(5376), dim3(256), 0, stream>>>(x, Wa, Wp, xb, wat, wpt, cs);
    qkv_gemm_kernel<<<dim3(24, 64), dim3(256), 0, stream>>>(xb, wat, ba, cs, qg, kg, vtg);
    flash_kernel<<<dim3(1024), dim3(512), 0, stream>>>(qg, kg, vtg, aob);
    proj_gemm_kernel<<<dim3(8, 64), dim3(256), 0, stream>>>(aob, wpt, bp, out);
}

// Round 6
// 257.997 us; speedup vs baseline: 9.0719x; 1.0477x over previous
//
#include <hip/hip_runtime.h>
#include <hip/hip_bf16.h>
#include <math.h>

// (B,T,E,H) = (4,2048,1024,16), D=64
#define TT 2048
#define HH 16

typedef short s16x8 __attribute__((ext_vector_type(8)));
typedef float f32x4 __attribute__((ext_vector_type(4)));

#define F4(p) (*reinterpret_cast<const float4*>(p))

__device__ __forceinline__ void gload16(const void* g, void* l) {
    __builtin_amdgcn_global_load_lds(
        (const __attribute__((address_space(1))) void*)g,
        (__attribute__((address_space(3))) void*)l, 16, 0, 0);
}

__device__ __forceinline__ ushort bf1(float a) {
    __hip_bfloat16 h = __float2bfloat16(a);
    union { __hip_bfloat16 h1; ushort u; } c; c.h1 = h; return c.u;
}
__device__ __forceinline__ uint pack_bf2(float a, float b) {
    __hip_bfloat162 h = __float22bfloat162_rn(make_float2(a, b));
    union { __hip_bfloat162 h2; uint u; } c; c.h2 = h; return c.u;
}

// raw v_exp_f32 (no libm special-case bloat)
__device__ __forceinline__ float fexp2(float x) {
#if __has_builtin(__builtin_amdgcn_exp2f)
    return __builtin_amdgcn_exp2f(x);
#else
    float r; asm("v_exp_f32 %0, %1" : "=v"(r) : "v"(x)); return r;
#endif
}

// ---------------------------------------------------------------------------
// Prep kernel (fused): rope table | x->bf16 | W_attn^T bf16 | W_proj^T bf16
// Block ranges: [0,256) rope, [256,4352) convert, [4352,5120) Wa, [5120,5376) Wp
// ---------------------------------------------------------------------------
__global__ __launch_bounds__(256) void prep_kernel(
    const float* __restrict__ x, const float* __restrict__ Wa,
    const float* __restrict__ Wp, ushort* __restrict__ xb,
    ushort* __restrict__ wat, ushort* __restrict__ wpt, float2* __restrict__ cs)
{
    __shared__ float tsh[64][65];
    const int blk = blockIdx.x;
    const int tid = threadIdx.x;

    if (blk < 256) {
        int idx = blk * 256 + tid;
        int t = idx >> 5;
        int i = idx & 31;
        double inv_d = exp(((double)(-2 * i) / 64.0) * log(10000.0));
        float invf = (float)inv_d;
        float freq = (float)t * invf;
        double df = (double)freq;
        cs[idx] = make_float2((float)cos(df), (float)sin(df));
    } else if (blk < 4352) {
        size_t i = (size_t)(blk - 256) * 2048 + (size_t)tid * 8;
        float4 a = F4(&x[i]); float4 b = F4(&x[i + 4]);
        s16x8 v;
        v[0] = bf1(a.x); v[1] = bf1(a.y); v[2] = bf1(a.z); v[3] = bf1(a.w);
        v[4] = bf1(b.x); v[5] = bf1(b.y); v[6] = bf1(b.z); v[7] = bf1(b.w);
        *reinterpret_cast<s16x8*>(&xb[i]) = v;
    } else {
        const float* in; ushort* out; int R, C, bx, by;
        if (blk < 5120) { int r = blk - 4352; in = Wa; out = wat; R = 1024; C = 3072; bx = r % 48; by = r / 48; }
        else            { int r = blk - 5120; in = Wp; out = wpt; R = 1024; C = 1024; bx = r & 15; by = r >> 4; }
        int r0 = by * 64, c0 = bx * 64;
        int ix = tid & 15, iy = tid >> 4;
#pragma unroll
        for (int j = 0; j < 4; ++j) {
            float4 v = F4(&in[(size_t)(r0 + iy + j * 16) * C + c0 + ix * 4]);
            tsh[iy + j * 16][ix * 4 + 0] = v.x;
            tsh[iy + j * 16][ix * 4 + 1] = v.y;
            tsh[iy + j * 16][ix * 4 + 2] = v.z;
            tsh[iy + j * 16][ix * 4 + 3] = v.w;
        }
        __syncthreads();
        int oc = tid >> 2, seg = tid & 3;
        s16x8 u0, u1;
#pragma unroll
        for (int i = 0; i < 8; ++i) u0[i] = bf1(tsh[seg * 16 + i][oc]);
#pragma unroll
        for (int i = 0; i < 8; ++i) u1[i] = bf1(tsh[seg * 16 + 8 + i][oc]);
        ushort* dst = &out[(size_t)(c0 + oc) * R + r0 + seg * 16];
        *reinterpret_cast<s16x8*>(dst) = u0;
        *reinterpret_cast<s16x8*>(dst + 8) = u1;
    }
}

// ---------------------------------------------------------------------------
// QKV GEMM bf16 MFMA + bias + RoPE. q pre-scaled by 0.125*log2(e).
// Outputs: q,k [bh][2048 t][64 d] bf16; v TRANSPOSED [bh][64 d][2048 t] bf16.
// BM=BN=128, BK=64, 256 thr (4 waves), dbuf LDS, XOR swizzle, XCD-swizzled grid.
// ---------------------------------------------------------------------------
__global__ __launch_bounds__(256, 2) void qkv_gemm_kernel(
    const ushort* __restrict__ xb,    // [8192][1024] bf16
    const ushort* __restrict__ wat,   // [3072][1024] bf16 (W^T)
    const float* __restrict__ bias,   // [3072]
    const float2* __restrict__ cs,    // [2048][32]
    ushort* __restrict__ qg, ushort* __restrict__ kg, ushort* __restrict__ vt)
{
    __shared__ ushort As[2][8192];   // [128 m][64 k]
    __shared__ ushort Bs[2][8192];   // [128 n][64 k]

    const int tid = threadIdx.x;
    const int lane = tid & 63, wid = tid >> 6;
    const int lane15 = lane & 15, kgrp = lane >> 4;
    const int wr = wid >> 1, wc = wid & 1;
    // XCD-bijective swizzle: 1536 blocks, 192/XCD
    const int bid = blockIdx.x;
    const int sbid = (bid & 7) * 192 + (bid >> 3);
    const int n0 = (sbid % 24) * 128, m0 = (sbid / 24) * 128;
    const int swz = (lane15 & 7) << 4;
    const int srcsw = ((lane & 7) ^ ((lane >> 3) & 7)) * 8;
    const int kgrp16 = kgrp * 16;
    const float SCL = 0.125f * 1.44269504088896f;

    f32x4 acc[4][4] = {};

#define STAGE_QKV(bufi, kofs)                                                     \
    do {                                                                          \
        _Pragma("unroll")                                                         \
        for (int i_ = 0; i_ < 4; ++i_) {                                          \
            int c_ = wid * 4 + i_;                                                \
            gload16(xb + (size_t)(m0 + c_ * 8 + (lane >> 3)) * 1024 + (kofs) + srcsw, \
                    &As[bufi][c_ * 512]);                                         \
            gload16(wat + (size_t)(n0 + c_ * 8 + (lane >> 3)) * 1024 + (kofs) + srcsw, \
                    &Bs[bufi][c_ * 512]);                                         \
        }                                                                         \
    } while (0)

    STAGE_QKV(0, 0);
    int buf = 0;
    for (int kt = 0; kt < 16; ++kt) {
        __syncthreads();
        if (kt < 15) STAGE_QKV(buf ^ 1, (kt + 1) * 64);
        const char* Ap = (const char*)As[buf];
        const char* Bp = (const char*)Bs[buf];
#pragma unroll
        for (int ks = 0; ks < 2; ++ks) {
            s16x8 af[4], bfv[4];
            const int kb = (ks * 64 + kgrp16) ^ swz;
#pragma unroll
            for (int f = 0; f < 4; ++f) {
                int row = wr * 64 + f * 16 + lane15;
                af[f] = *reinterpret_cast<const s16x8*>(Ap + row * 128 + kb);
            }
#pragma unroll
            for (int g = 0; g < 4; ++g) {
                int row = wc * 64 + g * 16 + lane15;
                bfv[g] = *reinterpret_cast<const s16x8*>(Bp + row * 128 + kb);
            }
            __builtin_amdgcn_s_setprio(1);
#pragma unroll
            for (int f = 0; f < 4; ++f)
#pragma unroll
                for (int g = 0; g < 4; ++g)
                    acc[f][g] = __builtin_amdgcn_mfma_f32_16x16x32_bf16(
                        af[f], bfv[g], acc[f][g], 0, 0, 0);
            __builtin_amdgcn_s_setprio(0);
        }
        buf ^= 1;
    }

    // epilogue: bias + rope(q,k) + scatter
#pragma unroll
    for (int g = 0; g < 4; ++g) {
        const int n = n0 + wc * 64 + g * 16 + lane15;
        const int sec = n >> 10;
        const int e = n & 1023;
        const int hh = e >> 6, d = e & 63;
        const float bsv = bias[n];
#pragma unroll
        for (int f = 0; f < 4; ++f) {
            const int mb = m0 + wr * 64 + f * 16 + kgrp * 4;
            const int bb = mb >> 11;
            const int t0 = mb & 2047;
            if (sec == 2) {
                float v0 = acc[f][g][0] + bsv, v1 = acc[f][g][1] + bsv;
                float v2 = acc[f][g][2] + bsv, v3 = acc[f][g][3] + bsv;
                uint2 u = make_uint2(pack_bf2(v0, v1), pack_bf2(v2, v3));
                *reinterpret_cast<uint2*>(
                    &vt[((size_t)(bb * HH + hh) * 64 + d) * TT + t0]) = u;
            } else {
                ushort* dst = (sec == 0) ? qg : kg;
#pragma unroll
                for (int r = 0; r < 4; ++r) {
                    float v = acc[f][g][r] + bsv;
                    float p = __shfl_xor(v, 1);
                    float2 c2 = cs[(t0 + r) * 32 + (d >> 1)];
                    float rv = (d & 1) ? (p * c2.y + v * c2.x) : (v * c2.x - p * c2.y);
                    if (sec == 0) rv *= SCL;
                    dst[((size_t)(bb * HH + hh) * TT + t0 + r) * 64 + d] = bf1(rv);
                }
            }
        }
    }
#undef STAGE_QKV
}

// ---------------------------------------------------------------------------
// Flash attention bf16 MFMA. 512 thr (8 waves x 16 q-rows), q-tile 128,
// kv-tile 64 double-buffered. Q in registers; LDS 48KB -> 3 blocks/CU.
// S^T = mfma(K,Q^T); in-lane online softmax (raw v_exp_f32, defer-max THR=8,
// max3 trees); O^T = mfma(V^T,P^T) with a 5th all-ones A-fragment
// accumulating l = sum(P) in the MFMA pipe (no VALU row-sum).
// ---------------------------------------------------------------------------
__global__ __launch_bounds__(512, 6) void flash_kernel(
    const ushort* __restrict__ qg, const ushort* __restrict__ kg,
    const ushort* __restrict__ vt, ushort* __restrict__ aob)
{
    __shared__ ushort K_s[2][4096];   // [64 kv][64 d]
    __shared__ ushort V_s[2][4096];   // [64 d][64 kv]
    __shared__ ushort P_s[8192];      // [8 waves][16 q][64 kv]; reused as output

    const int tid = threadIdx.x;
    const int lane = tid & 63, wid = tid >> 6;
    const int lane15 = lane & 15, kgrp = lane >> 4;
    const int j = blockIdx.x;
    const int qt = 15 - (j >> 6);               // work-descending
    const int bh = j & 63;
    const int b = bh >> 4, h = bh & 15;
    const int q0 = qt * 128;
    const int wq = wid * 16;
    const int wq_abs = q0 + wq;
    const int swz = (lane15 & 7) << 4;
    const int srcsw = ((lane & 7) ^ ((lane >> 3) & 7)) * 8;
    const int kgrp16 = kgrp * 16;
    const int nt = 2 * qt + 2;

    const ushort* qp = qg + (size_t)bh * TT * 64;
    const ushort* kp = kg + (size_t)bh * TT * 64;
    const ushort* vp = vt + (size_t)bh * 64 * TT;
    char* Pw = (char*)P_s + wid * 2048;          // this wave's 16 P rows

#define STAGE_KV(bufi, kv0_)                                                      \
    do {                                                                          \
        gload16(kp + (size_t)((kv0_) + wid * 8 + (lane >> 3)) * 64 + srcsw,       \
                &K_s[bufi][wid * 512]);                                           \
        gload16(vp + (size_t)(wid * 8 + (lane >> 3)) * TT + (kv0_) + srcsw,       \
                &V_s[bufi][wid * 512]);                                           \
    } while (0)

    // Q fragments straight to registers (this wave's 16 rows)
    const ushort* qrow = qp + (size_t)(q0 + wq + lane15) * 64 + kgrp * 8;
    s16x8 qfr[2];
    qfr[0] = *reinterpret_cast<const s16x8*>(qrow);
    qfr[1] = *reinterpret_cast<const s16x8*>(qrow + 32);

    // all-ones bf16 A-fragment (for l = sum(P) via MFMA)
    s16x8 ones;
#pragma unroll
    for (int e = 0; e < 8; ++e) ones[e] = (short)0x3F80;

    STAGE_KV(0, 0);

    f32x4 o[5] = {};                  // o[0..3] = O^T rows, o[4] = l (ones row)
    float mreg = -3.0e38f;

    int buf = 0;
    for (int t = 0; t < nt; ++t) {
        __syncthreads();                         // staged tile landed (vmcnt0)
        if (t + 1 < nt) STAGE_KV(buf ^ 1, (t + 1) * 64);

        const int kv0 = t * 64;
        if (kv0 <= wq_abs + 15) {                // skip fully-masked tiles
            const char* Kp = (const char*)K_s[buf];
            const char* Vp = (const char*)V_s[buf];

            // ---- S^T = K . Q^T ----
            f32x4 sacc[4] = {};
#pragma unroll
            for (int ks = 0; ks < 2; ++ks) {
                const int kb = (ks * 64 + kgrp16) ^ swz;
                s16x8 ka[4];
#pragma unroll
                for (int kf = 0; kf < 4; ++kf)
                    ka[kf] = *reinterpret_cast<const s16x8*>(Kp + (kf * 16 + lane15) * 128 + kb);
                __builtin_amdgcn_s_setprio(1);
#pragma unroll
                for (int kf = 0; kf < 4; ++kf)
                    sacc[kf] = __builtin_amdgcn_mfma_f32_16x16x32_bf16(
                        ka[kf], qfr[ks], sacc[kf], 0, 0, 0);
                __builtin_amdgcn_s_setprio(0);
            }

            // ---- online softmax (per lane: 16 kv values, one q col) ----
            const int qglob = q0 + wq + lane15;
            if (kv0 + 63 > wq_abs) {             // mask only near diagonal
#pragma unroll
                for (int kf = 0; kf < 4; ++kf)
#pragma unroll
                    for (int r = 0; r < 4; ++r) {
                        int kvg = kv0 + kf * 16 + kgrp * 4 + r;
                        if (kvg > qglob) sacc[kf][r] = -3.0e38f;
                    }
            }
            // max over 16 values via v_max3 trees
            float t0m = fmaxf(fmaxf(sacc[0][0], sacc[0][1]), sacc[0][2]);
            float t1m = fmaxf(fmaxf(sacc[0][3], sacc[1][0]), sacc[1][1]);
            float t2m = fmaxf(fmaxf(sacc[1][2], sacc[1][3]), sacc[2][0]);
            float t3m = fmaxf(fmaxf(sacc[2][1], sacc[2][2]), sacc[2][3]);
            float t4m = fmaxf(fmaxf(sacc[3][0], sacc[3][1]), sacc[3][2]);
            float mx = fmaxf(fmaxf(fmaxf(t0m, t1m), fmaxf(t2m, t3m)),
                             fmaxf(t4m, sacc[3][3]));
            mx = fmaxf(mx, __shfl_xor(mx, 16));
            mx = fmaxf(mx, __shfl_xor(mx, 32));
            if (!__all(mx <= mreg + 8.f)) {      // defer-max rescale
                const float mnew = fmaxf(mreg, mx);
                const float fs = fexp2(mreg - mnew);
#pragma unroll
                for (int df = 0; df < 5; ++df) o[df] *= fs;
                mreg = mnew;
            }
#pragma unroll
            for (int kf = 0; kf < 4; ++kf) {
                float p0 = fexp2(sacc[kf][0] - mreg);
                float p1 = fexp2(sacc[kf][1] - mreg);
                float p2 = fexp2(sacc[kf][2] - mreg);
                float p3 = fexp2(sacc[kf][3] - mreg);
                uint2 u = make_uint2(pack_bf2(p0, p1), pack_bf2(p2, p3));
                int kvb = (kf * 32 + kgrp * 8) ^ swz;
                *reinterpret_cast<uint2*>(Pw + lane15 * 128 + kvb) = u;
            }

            // ---- O^T += V^T . P^T  (+ ones row -> l) ----
#pragma unroll
            for (int ks = 0; ks < 2; ++ks) {
                const int kb = (ks * 64 + kgrp16) ^ swz;
                s16x8 va[4], pb;
#pragma unroll
                for (int df = 0; df < 4; ++df)
                    va[df] = *reinterpret_cast<const s16x8*>(Vp + (df * 16 + lane15) * 128 + kb);
                pb = *reinterpret_cast<const s16x8*>(Pw + lane15 * 128 + kb);
                __builtin_amdgcn_s_setprio(1);
#pragma unroll
                for (int df = 0; df < 4; ++df)
                    o[df] = __builtin_amdgcn_mfma_f32_16x16x32_bf16(
                        va[df], pb, o[df], 0, 0, 0);
                o[4] = __builtin_amdgcn_mfma_f32_16x16x32_bf16(
                    ones, pb, o[4], 0, 0, 0);
                __builtin_amdgcn_s_setprio(0);
            }
        }
        buf ^= 1;
    }

    // ---- epilogue: normalize by l = o[4][0], repack via P_s, store ----
    {
        const float inv = 1.0f / o[4][0];
        const int row = wq + lane15;
#pragma unroll
        for (int df = 0; df < 4; ++df) {
            float p0 = o[df][0] * inv, p1 = o[df][1] * inv;
            float p2 = o[df][2] * inv, p3 = o[df][3] * inv;
            uint2 u = make_uint2(pack_bf2(p0, p1), pack_bf2(p2, p3));
            int db = (df * 32 + kgrp * 8) ^ ((row & 7) << 4);
            *reinterpret_cast<uint2*>((char*)P_s + row * 128 + db) = u;
        }
    }
    __syncthreads();
    {
        const int q = tid >> 2, seg = tid & 3;
        ushort* orow = aob + ((size_t)(b * TT + q0 + q)) * 1024 + h * 64 + seg * 16;
        int p0 = (seg * 32) ^ ((q & 7) << 4);
        int p1 = (seg * 32 + 16) ^ ((q & 7) << 4);
        s16x8 v0 = *reinterpret_cast<const s16x8*>((const char*)P_s + q * 128 + p0);
        s16x8 v1 = *reinterpret_cast<const s16x8*>((const char*)P_s + q * 128 + p1);
        *reinterpret_cast<s16x8*>(orow) = v0;
        *reinterpret_cast<s16x8*>(orow + 8) = v1;
    }
#undef STAGE_KV
}

// ---------------------------------------------------------------------------
// Proj GEMM bf16 MFMA: ao[8192x1024] @ Wp[1024x1024] + bias -> f32 out
// XCD-swizzled grid (512 blocks, 64/XCD).
// ---------------------------------------------------------------------------
__global__ __launch_bounds__(256, 2) void proj_gemm_kernel(
    const ushort* __restrict__ ab,    // [8192][1024] bf16
    const ushort* __restrict__ wpt,   // [1024][1024] bf16 (W^T)
    const float* __restrict__ bias,   // [1024]
    float* __restrict__ out)          // [8192][1024] f32
{
    __shared__ ushort As[2][8192];
    __shared__ ushort Bs[2][8192];

    const int tid = threadIdx.x;
    const int lane = tid & 63, wid = tid >> 6;
    const int lane15 = lane & 15, kgrp = lane >> 4;
    const int wr = wid >> 1, wc = wid & 1;
    const int bid = blockIdx.x;
    const int sbid = (bid & 7) * 64 + (bid >> 3);
    const int n0 = (sbid & 7) * 128, m0 = (sbid >> 3) * 128;
    const int swz = (lane15 & 7) << 4;
    const int srcsw = ((lane & 7) ^ ((lane >> 3) & 7)) * 8;
    const int kgrp16 = kgrp * 16;

    f32x4 acc[4][4] = {};

#define STAGE_PRJ(bufi, kofs)                                                     \
    do {                                                                          \
        _Pragma("unroll")                                                         \
        for (int i_ = 0; i_ < 4; ++i_) {                                          \
            int c_ = wid * 4 + i_;                                                \
            gload16(ab + (size_t)(m0 + c_ * 8 + (lane >> 3)) * 1024 + (kofs) + srcsw, \
                    &As[bufi][c_ * 512]);                                         \
            gload16(wpt + (size_t)(n0 + c_ * 8 + (lane >> 3)) * 1024 + (kofs) + srcsw, \
                    &Bs[bufi][c_ * 512]);                                         \
        }                                                                         \
    } while (0)

    STAGE_PRJ(0, 0);
    int buf = 0;
    for (int kt = 0; kt < 16; ++kt) {
        __syncthreads();
        if (kt < 15) STAGE_PRJ(buf ^ 1, (kt + 1) * 64);
        const char* Ap = (const char*)As[buf];
        const char* Bp = (const char*)Bs[buf];
#pragma unroll
        for (int ks = 0; ks < 2; ++ks) {
            s16x8 af[4], bfv[4];
            const int kb = (ks * 64 + kgrp16) ^ swz;
#pragma unroll
            for (int f = 0; f < 4; ++f) {
                int row = wr * 64 + f * 16 + lane15;
                af[f] = *reinterpret_cast<const s16x8*>(Ap + row * 128 + kb);
            }
#pragma unroll
            for (int g = 0; g < 4; ++g) {
                int row = wc * 64 + g * 16 + lane15;
                bfv[g] = *reinterpret_cast<const s16x8*>(Bp + row * 128 + kb);
            }
            __builtin_amdgcn_s_setprio(1);
#pragma unroll
            for (int f = 0; f < 4; ++f)
#pragma unroll
                for (int g = 0; g < 4; ++g)
                    acc[f][g] = __builtin_amdgcn_mfma_f32_16x16x32_bf16(
                        af[f], bfv[g], acc[f][g], 0, 0, 0);
            __builtin_amdgcn_s_setprio(0);
        }
        buf ^= 1;
    }

#pragma unroll
    for (int g = 0; g < 4; ++g) {
        const int n = n0 + wc * 64 + g * 16 + lane15;
        const float bv = bias[n];
#pragma unroll
        for (int f = 0; f < 4; ++f)
#pragma unroll
            for (int r = 0; r < 4; ++r) {
                const int m = m0 + wr * 64 + f * 16 + kgrp * 4 + r;
                out[(size_t)m * 1024 + n] = acc[f][g][r] + bv;
            }
    }
#undef STAGE_PRJ
}

// ---------------------------------------------------------------------------
extern "C" void kernel_launch(void* const* d_in, const int* in_sizes, int n_in,
                              void* d_out, int out_size, void* d_ws, size_t ws_size,
                              hipStream_t stream) {
    const float* x  = (const float*)d_in[0];   // [4,2048,1024]
    const float* Wa = (const float*)d_in[1];   // [1024,3072]
    const float* ba = (const float*)d_in[2];   // [3072]
    const float* Wp = (const float*)d_in[3];   // [1024,1024]
    const float* bp = (const float*)d_in[4];   // [1024]
    float* out = (float*)d_out;                // [4,2048,1024]

    // workspace (byte offsets)
    char* ws = (char*)d_ws;
    ushort* xb  = (ushort*)(ws + 0);            // 16.8 MB  [8192][1024]
    ushort* wat = (ushort*)(ws + 16777216);     // 6.3 MB   [3072][1024]
    ushort* wpt = (ushort*)(ws + 23068672);     // 2.1 MB   [1024][1024]
    ushort* qg  = (ushort*)(ws + 25165824);     // 16.8 MB  [bh][2048][64]
    ushort* kg  = (ushort*)(ws + 41943040);     // 16.8 MB  [bh][2048][64]
    ushort* vtg = (ushort*)(ws + 58720256);     // 16.8 MB  [bh][64][2048]
    ushort* aob = (ushort*)(ws + 75497472);     // 16.8 MB  [8192][1024]
    float2* cs  = (float2*)(ws + 92274688);     // 0.5 MB

    prep_kernel<<<dim3(5376), dim3(256), 0, stream>>>(x, Wa, Wp, xb, wat, wpt, cs);
    qkv_gemm_kernel<<<dim3(1536), dim3(256), 0, stream>>>(xb, wat, ba, cs, qg, kg, vtg);
    flash_kernel<<<dim3(1024), dim3(512), 0, stream>>>(qg, kg, vtg, aob);
    proj_gemm_kernel<<<dim3(512), dim3(256), 0, stream>>>(aob, wpt, bp, out);
}